// Round 16
// baseline (222.798 us; speedup 1.0000x reference)
//
#include <hip/hip_runtime.h>
#include <math.h>

#define BB 64
#define PP 100
#define NN 1000
#define DD 128
#define HH 8
#define QDQ 16
#define NTOT 1196
#define QROWS 16
#define LOG2E 1.44269504088896f
#define EXP2(x) __builtin_amdgcn_exp2f(x)

typedef float f2 __attribute__((ext_vector_type(2)));
typedef short s8v __attribute__((ext_vector_type(8)));
typedef float f16v __attribute__((ext_vector_type(16)));

static __device__ __forceinline__ f2 splat2(float v) { f2 r; r.x = v; r.y = v; return r; }
#define PKFMA(a, b, c) __builtin_elementwise_fma((a), (b), (c))

static __device__ __forceinline__ unsigned pkhi(float a, float b) {
  return (__float_as_uint(a) >> 16) | (__float_as_uint(b) & 0xffff0000u);
}
static __device__ __forceinline__ float truncbf(float a) {
  return __uint_as_float(__float_as_uint(a) & 0xffff0000u);
}
#define MFMA32(a, b, c) __builtin_amdgcn_mfma_f32_32x32x16_bf16((a), (b), (c), 0, 0, 0)

// ------- Kernel P: fused {q = q_first + x @ Wq^T} and {mask2 bf16 table} ------
// blocks 0..399: qcalc (16 bp-rows each); blocks 400..8591: mask2 rows (b,q).
__global__ __launch_bounds__(256) void k_prep(const float* __restrict__ x,
                                              const float* __restrict__ Wq,
                                              const float* __restrict__ qf,
                                              float* __restrict__ qout,
                                              const float* __restrict__ mask,
                                              unsigned short* __restrict__ m2) {
  __shared__ float sw[128 * 65];
  __shared__ float xs[QROWS * DD];
  int tid = threadIdx.x;

  if (blockIdx.x < 400) {
    int row0 = blockIdx.x * QROWS;
    for (int i = tid; i < QROWS * DD / 4; i += 256)
      ((float4*)xs)[i] = ((const float4*)(x + (size_t)row0 * DD))[i];

    int j = tid & 127, rr = tid >> 7;
    float acc[8];
#pragma unroll
    for (int i = 0; i < 8; ++i) acc[i] = 0.f;

    for (int half = 0; half < 2; ++half) {
      __syncthreads();
      for (int idx = tid; idx < 128 * 64; idx += 256) {
        int jj = idx >> 6, dl = idx & 63;
        sw[jj * 65 + dl] = Wq[jj * DD + half * 64 + dl];
      }
      __syncthreads();
#pragma unroll
      for (int ri = 0; ri < 8; ++ri) {
        int r = 2 * ri + rr;
        float a = acc[ri];
#pragma unroll 16
        for (int dl = 0; dl < 64; ++dl)
          a += xs[r * DD + half * 64 + dl] * sw[j * 65 + dl];
        acc[ri] = a;
      }
    }
#pragma unroll
    for (int ri = 0; ri < 8; ++ri) {
      int bp = row0 + 2 * ri + rr;
      int b = bp / PP, p = bp % PP;
      int h = j >> 4, qd = j & 15;
      size_t qi = ((size_t)(b * HH + h) * PP + p) * QDQ + qd;
      qout[qi] = acc[ri] + qf[qi];
    }
  } else {
    int t2 = blockIdx.x - 400;
    int b = t2 >> 7, q = t2 & 127;
    unsigned short* dst = m2 + (size_t)(b * 128 + q) * 1280;
    const float* srow = mask + ((size_t)b * PP + (q < PP ? q : PP - 1)) * NN;
    for (int j = tid; j < 1280; j += 256) {
      int h = j >= 640 ? 1 : 0;
      int jj = j - h * 640;
      float val;
      if (q >= PP || jj >= 598) {
        val = -1e4f;
      } else {
        int n = h * 598 + jj;
        val = (n < NN) ? srow[n] * LOG2E - 20.f : -20.f;
      }
      dst[j] = (unsigned short)(__float_as_uint(val) >> 16);
    }
  }
}

// ---------------- Kernel B: MFMA MHA partial (split-bf16, swapped QK^T) -------
// grid = 1024 (XCD-swizzled: 512 bh * 2 halves); block = 256 (4 waves).
// v4 (vs r15): register-prefetch of next chunk's k/v float4s so global latency
// overlaps the MFMA+exp compute phase. All layouts/strides/math r15-identical.
__global__ __launch_bounds__(256) void k_mha(const float* __restrict__ kk,
                                             const float* __restrict__ vv,
                                             const float* __restrict__ qws,
                                             const unsigned short* __restrict__ m2,
                                             float* __restrict__ part) {
  int bid = blockIdx.x;
  int swz = (bid & 7) * 128 + (bid >> 3);
  int bh = swz >> 1, half = swz & 1;
  int b = bh >> 3;
  int tid = threadIdx.x;
  int w = tid >> 6, lane = tid & 63;
  int L = lane >> 5, ln = lane & 31;
  bool lo = (L == 0);

  __shared__ __align__(16) char pool[27264];
  char* KspB = pool;                 // [128][80B]: hi 32B | lo 32B | pad 16B
  char* VThB = pool + 10240;         // ushort [16][136] : V^T hi
  char* VTlB = pool + 14592;         // ushort [16][136] : V^T lo
  char* QhB  = pool + 18944;         // ushort [128][16]
  char* QlB  = pool + 23040;

  // ---- stage Q (scaled, split) ----
  {
    const float* qrow = qws + (size_t)bh * (PP * QDQ);
    for (int i = tid; i < 128 * 16; i += 256) {
      int p = i >> 4, qd = i & 15;
      float v = (p < PP) ? qrow[p * QDQ + qd] * (0.25f * LOG2E) : 0.f;
      ((unsigned short*)QhB)[i] = (unsigned short)(__float_as_uint(v) >> 16);
      float rl = v - truncbf(v);
      ((unsigned short*)QlB)[i] = (unsigned short)(__float_as_uint(rl) >> 16);
    }
  }

  const float4* kf4 = (const float4*)kk + (size_t)bh * NTOT * 4;
  const float4* vf4 = (const float4*)vv + (size_t)bh * NTOT * 4;

#define GLOAD(c, rep, k4v, v4v) { \
    int f = tid + (rep) * 256; \
    int jl = (c) * 128 + (f >> 2); jl = jl < 598 ? jl : 597; \
    size_t gidx = (size_t)(half * 598 + jl) * 4 + (f & 3); \
    k4v = kf4[gidx]; v4v = vf4[gidx]; }

#define STORE1(rep, k4v, v4v) { \
    int f = tid + (rep) * 256; \
    int key_l = f >> 2, qd0 = (f & 3) << 2; \
    unsigned kh01 = pkhi(k4v.x, k4v.y), kh23 = pkhi(k4v.z, k4v.w); \
    float r0 = k4v.x - truncbf(k4v.x), r1 = k4v.y - truncbf(k4v.y); \
    float r2 = k4v.z - truncbf(k4v.z), r3 = k4v.w - truncbf(k4v.w); \
    *(uint2*)(KspB + key_l * 80 + qd0 * 2) = make_uint2(kh01, kh23); \
    *(uint2*)(KspB + key_l * 80 + 32 + qd0 * 2) = make_uint2(pkhi(r0, r1), pkhi(r2, r3)); \
    ((unsigned short*)VThB)[(qd0 + 0) * 136 + key_l] = (unsigned short)(__float_as_uint(v4v.x) >> 16); \
    ((unsigned short*)VThB)[(qd0 + 1) * 136 + key_l] = (unsigned short)(__float_as_uint(v4v.y) >> 16); \
    ((unsigned short*)VThB)[(qd0 + 2) * 136 + key_l] = (unsigned short)(__float_as_uint(v4v.z) >> 16); \
    ((unsigned short*)VThB)[(qd0 + 3) * 136 + key_l] = (unsigned short)(__float_as_uint(v4v.w) >> 16); \
    float w0 = v4v.x - truncbf(v4v.x), w1 = v4v.y - truncbf(v4v.y); \
    float w2 = v4v.z - truncbf(v4v.z), w3 = v4v.w - truncbf(v4v.w); \
    ((unsigned short*)VTlB)[(qd0 + 0) * 136 + key_l] = (unsigned short)(__float_as_uint(w0) >> 16); \
    ((unsigned short*)VTlB)[(qd0 + 1) * 136 + key_l] = (unsigned short)(__float_as_uint(w1) >> 16); \
    ((unsigned short*)VTlB)[(qd0 + 2) * 136 + key_l] = (unsigned short)(__float_as_uint(w2) >> 16); \
    ((unsigned short*)VTlB)[(qd0 + 3) * 136 + key_l] = (unsigned short)(__float_as_uint(w3) >> 16); }

  f16v Oacc[4];
  float lacc[4];
#pragma unroll
  for (int qt = 0; qt < 4; ++qt) {
    lacc[qt] = 0.f;
#pragma unroll
    for (int r = 0; r < 16; ++r) Oacc[qt][r] = 0.f;
  }
  s8v QhF[4], QlF[4];

  float4 k4a, v4a, k4b, v4b;
  GLOAD(0, 0, k4a, v4a)
  GLOAD(0, 1, k4b, v4b)

  for (int c = 0; c < 5; ++c) {
    __syncthreads();                  // prior compute done; LDS writable
    STORE1(0, k4a, v4a)
    STORE1(1, k4b, v4b)
    __syncthreads();
    if (c < 4) {                      // prefetch next chunk (overlaps compute)
      GLOAD(c + 1, 0, k4a, v4a)
      GLOAD(c + 1, 1, k4b, v4b)
    }
    if (c == 0) {
#pragma unroll
      for (int qt = 0; qt < 4; ++qt) {
        int qr = qt * 32 + ln;
        QhF[qt] = *(const s8v*)(QhB + qr * 32 + L * 16);
        QlF[qt] = *(const s8v*)(QlB + qr * 32 + L * 16);
      }
    }
    // ---- compute this wave's 32-key tile ----
    int ktb = w * 32;
    s8v KhF = *(const s8v*)(KspB + (ktb + ln) * 80 + L * 16);
    s8v KlF = *(const s8v*)(KspB + (ktb + ln) * 80 + 32 + L * 16);
    int vr = ln & 15;
    s8v VhS0 = *(const s8v*)(VThB + vr * 272 + (ktb + L * 8) * 2);
    s8v VhS1 = *(const s8v*)(VThB + vr * 272 + (ktb + 16 + L * 8) * 2);
    s8v VlS0 = *(const s8v*)(VTlB + vr * 272 + (ktb + L * 8) * 2);
    s8v VlS1 = *(const s8v*)(VTlB + vr * 272 + (ktb + 16 + L * 8) * 2);
    size_t mkey = (size_t)half * 640 + c * 128 + ktb + 4 * L;
#pragma unroll
    for (int qt = 0; qt < 4; ++qt) {
      const unsigned short* mrow = m2 + (size_t)(b * 128 + qt * 32 + ln) * 1280 + mkey;
      f16v acc;
#pragma unroll
      for (int g = 0; g < 4; ++g) {
        uint2 md = *(const uint2*)(mrow + g * 8);
        acc[g * 4 + 0] = __uint_as_float(md.x << 16);
        acc[g * 4 + 1] = __uint_as_float(md.x & 0xffff0000u);
        acc[g * 4 + 2] = __uint_as_float(md.y << 16);
        acc[g * 4 + 3] = __uint_as_float(md.y & 0xffff0000u);
      }
      acc = MFMA32(KhF, QhF[qt], acc);
      acc = MFMA32(KhF, QlF[qt], acc);
      acc = MFMA32(KlF, QhF[qt], acc);
      float p[16];
      float ls = 0.f;
#pragma unroll
      for (int r = 0; r < 16; ++r) { p[r] = EXP2(acc[r]); ls += p[r]; }
      lacc[qt] += ls;
#pragma unroll
      for (int s = 0; s < 2; ++s) {
        unsigned a0 = pkhi(p[8 * s + 0], p[8 * s + 1]), a1 = pkhi(p[8 * s + 2], p[8 * s + 3]);
        unsigned b0 = pkhi(p[8 * s + 4], p[8 * s + 5]), b1 = pkhi(p[8 * s + 6], p[8 * s + 7]);
        unsigned m0 = lo ? b0 : a0;          // single-shuffle half-exchange
        unsigned m1 = lo ? b1 : a1;
        unsigned s0 = __shfl_xor(m0, 32);
        unsigned s1 = __shfl_xor(m1, 32);
        uint4 phu = make_uint4(lo ? a0 : s0, lo ? a1 : s1, lo ? s0 : b0, lo ? s1 : b1);
        float t0 = p[8 * s + 0] - truncbf(p[8 * s + 0]), t1 = p[8 * s + 1] - truncbf(p[8 * s + 1]);
        float t2 = p[8 * s + 2] - truncbf(p[8 * s + 2]), t3 = p[8 * s + 3] - truncbf(p[8 * s + 3]);
        float t4 = p[8 * s + 4] - truncbf(p[8 * s + 4]), t5 = p[8 * s + 5] - truncbf(p[8 * s + 5]);
        float t6 = p[8 * s + 6] - truncbf(p[8 * s + 6]), t7 = p[8 * s + 7] - truncbf(p[8 * s + 7]);
        unsigned c0 = pkhi(t0, t1), c1 = pkhi(t2, t3);
        unsigned e0 = pkhi(t4, t5), e1 = pkhi(t6, t7);
        unsigned n0 = lo ? e0 : c0;
        unsigned n1 = lo ? e1 : c1;
        unsigned u0 = __shfl_xor(n0, 32);
        unsigned u1 = __shfl_xor(n1, 32);
        uint4 plu = make_uint4(lo ? c0 : u0, lo ? c1 : u1, lo ? u0 : e0, lo ? u1 : e1);
        s8v APh = *(s8v*)&phu;
        s8v APl = *(s8v*)&plu;
        s8v Vh = s ? VhS1 : VhS0;
        s8v Vl = s ? VlS1 : VlS0;
        Oacc[qt] = MFMA32(APh, Vh, Oacc[qt]);
        Oacc[qt] = MFMA32(APh, Vl, Oacc[qt]);
        Oacc[qt] = MFMA32(APl, Vh, Oacc[qt]);
      }
    }
  }

  // ---- merge 4 waves -> part records [q][17] (unnormalized A + l) ----
  float lf[4];
#pragma unroll
  for (int qt = 0; qt < 4; ++qt) lf[qt] = lacc[qt] + __shfl_xor(lacc[qt], 32);

  __syncthreads();
  float* marea = (float*)pool;                 // [4][100][16]
  float* larea = (float*)(pool + 25600);       // [4][100]
  if (ln < 16) {
#pragma unroll
    for (int qt = 0; qt < 4; ++qt) {
#pragma unroll
      for (int r = 0; r < 16; ++r) {
        int q = qt * 32 + (r & 3) + 8 * (r >> 2) + 4 * L;
        if (q < PP) marea[(w * PP + q) * 16 + ln] = Oacc[qt][r];
      }
    }
  }
  if (lane < 32) {
#pragma unroll
    for (int qt = 0; qt < 4; ++qt) {
      int q = qt * 32 + ln;
      if (q < PP) larea[w * PP + q] = lf[qt];
    }
  }
  __syncthreads();
  for (int idx = tid; idx < PP * 17; idx += 256) {
    int q = idx / 17, e = idx % 17;
    float sv;
    if (e < 16)
      sv = marea[(0 * PP + q) * 16 + e] + marea[(1 * PP + q) * 16 + e]
         + marea[(2 * PP + q) * 16 + e] + marea[(3 * PP + q) * 16 + e];
    else
      sv = larea[0 * PP + q] + larea[1 * PP + q] + larea[2 * PP + q] + larea[3 * PP + q];
    part[((size_t)swz * PP + q) * 17 + e] = sv;
  }
#undef GLOAD
#undef STORE1
}

// ---------------- Kernel C: merge 2 halves (sum) + mh_combine (LDS GEMM) ------
__global__ __launch_bounds__(256) void k_combine(const float* __restrict__ part,
                                                 const float* __restrict__ MC,
                                                 float* __restrict__ mh) {
  __shared__ float sw[128 * 65];
  __shared__ float oc[QROWS * DD];
  int tid = threadIdx.x;
  int row0 = blockIdx.x * QROWS;

  for (int i = tid; i < QROWS * DD; i += 256) {
    int r = i >> 7, t = i & 127;
    int bp = row0 + r, b = bp / PP, p = bp % PP;
    int qd = t & 15, h = t >> 4;
    int bh = b * HH + h;
    const float* r0 = part + (((size_t)(bh * 2 + 0)) * PP + p) * 17;
    const float* r1 = part + (((size_t)(bh * 2 + 1)) * PP + p) * 17;
    float A = r0[qd] + r1[qd];
    float L = r0[16] + r1[16];
    oc[i] = A / L;
  }

  int j = tid & 127, rr = tid >> 7;
  float acc[8];
#pragma unroll
  for (int i = 0; i < 8; ++i) acc[i] = 0.f;

  for (int half = 0; half < 2; ++half) {
    __syncthreads();
    for (int idx = tid; idx < 128 * 64; idx += 256) {
      int jj = idx >> 6, dl = idx & 63;
      sw[jj * 65 + dl] = MC[jj * DD + half * 64 + dl];
    }
    __syncthreads();
#pragma unroll
    for (int ri = 0; ri < 8; ++ri) {
      int r = 2 * ri + rr;
      float a = acc[ri];
#pragma unroll 16
      for (int dl = 0; dl < 64; ++dl)
        a += oc[r * DD + half * 64 + dl] * sw[j * 65 + dl];
      acc[ri] = a;
    }
  }
#pragma unroll
  for (int ri = 0; ri < 8; ++ri) {
    int bp = row0 + 2 * ri + rr;
    mh[(size_t)bp * DD + j] = acc[ri];
  }
}

// ------- Kernel D: score2 (packed f32: two n-columns per accumulator) --------
__global__ __launch_bounds__(256) void k_score2(const float* __restrict__ mh,
                                                const float* __restrict__ shk,
                                                float* __restrict__ sc) {
  int bid = blockIdx.x;
  int swz = (bid & 7) * 128 + (bid >> 3);
  int b = swz >> 4, nt = swz & 15;
  int tid = threadIdx.x; int nl = tid & 31, pg = tid >> 5;
  __shared__ float A[PP * 132];
  for (int idx = tid; idx < PP * DD; idx += 256)
    A[(idx >> 7) * 132 + (idx & 127)] = mh[(size_t)b * PP * DD + idx];
  __syncthreads();

  int na = nt * 64 + nl, nb2 = na + 32;
  int nca = na < NN ? na : NN - 1, ncb = nb2 < NN ? nb2 : NN - 1;
  const float* S = shk + (size_t)b * DD * NN;
  f2 accv[13];
#pragma unroll
  for (int i = 0; i < 13; ++i) accv[i] = splat2(0.f);

  for (int d = 0; d < DD; d += 4) {
    f2 s0, s1, s2, s3;
    s0.x = S[(size_t)(d + 0) * NN + nca]; s0.y = S[(size_t)(d + 0) * NN + ncb];
    s1.x = S[(size_t)(d + 1) * NN + nca]; s1.y = S[(size_t)(d + 1) * NN + ncb];
    s2.x = S[(size_t)(d + 2) * NN + nca]; s2.y = S[(size_t)(d + 2) * NN + ncb];
    s3.x = S[(size_t)(d + 3) * NN + nca]; s3.y = S[(size_t)(d + 3) * NN + ncb];
#pragma unroll
    for (int i = 0; i < 13; ++i) {
      int p = pg + (i << 3);
      if (p < PP) {
        const float4 a4 = *(const float4*)&A[p * 132 + d];
        accv[i] = PKFMA(splat2(a4.x), s0, accv[i]);
        accv[i] = PKFMA(splat2(a4.y), s1, accv[i]);
        accv[i] = PKFMA(splat2(a4.z), s2, accv[i]);
        accv[i] = PKFMA(splat2(a4.w), s3, accv[i]);
      }
    }
  }
#pragma unroll
  for (int i = 0; i < 13; ++i) {
    int p = pg + (i << 3);
    if (p < PP) {
      size_t base = ((size_t)b * PP + p) * NN;
      if (na < NN) sc[base + na] = accv[i].x;
      if (nb2 < NN) sc[base + nb2] = accv[i].y;
    }
  }
}

// ------- Kernel E: tanh clip + edge bias + mask + row softmax (no max pass) ---
__global__ __launch_bounds__(256) void k_finsm(const float* __restrict__ sc,
                                               const float* __restrict__ eb,
                                               const int* __restrict__ cn,
                                               const float* __restrict__ mask,
                                               float* __restrict__ out) {
  int bid = blockIdx.x;
  int bp = (bid & 7) * 800 + (bid >> 3);
  int b = bp / PP;
  int t = threadIdx.x;
  int node = cn[bp];
  const float* scp = sc + (size_t)bp * NN;
  const float* ebp = eb + ((size_t)b * NN + node) * NN;
  const float* mp = mask + (size_t)bp * NN;
  const float inv_sqrtD = 0.08838834764831845f;

  float vals[4];
  float s = 0.f;
#pragma unroll
  for (int i = 0; i < 4; ++i) {
    int n = t + (i << 8);
    if (n < NN) {
      float z = scp[n] * inv_sqrtD;
      float e = EXP2(2.f * LOG2E * z);
      float th10 = 10.f - 20.f * __builtin_amdgcn_rcpf(e + 1.f);
      float lg = th10 + ebp[n] + mp[n];
      float e2 = EXP2(lg * LOG2E);
      vals[i] = e2;
      s += e2;
    } else {
      vals[i] = 0.f;
    }
  }
#pragma unroll
  for (int off = 32; off; off >>= 1) s += __shfl_xor(s, off);
  __shared__ float red[4];
  int w = t >> 6, lane = t & 63;
  if (lane == 0) red[w] = s;
  __syncthreads();
  s = (red[0] + red[1]) + (red[2] + red[3]);
  float inv = 1.f / s;
#pragma unroll
  for (int i = 0; i < 4; ++i) {
    int n = t + (i << 8);
    if (n < NN) out[(size_t)bp * NN + n] = vals[i] * inv;
  }
}

extern "C" void kernel_launch(void* const* d_in, const int* in_sizes, int n_in,
                              void* d_out, int out_size, void* d_ws, size_t ws_size,
                              hipStream_t stream) {
  const float* x    = (const float*)d_in[0];   // encoded_last_node (B,P,D)
  const float* mask = (const float*)d_in[1];   // ninf_mask (B,P,N)
  const float* qf   = (const float*)d_in[2];   // q_first (B,H,P,QD)
  const float* kk   = (const float*)d_in[3];   // k (B,H,NTOT,QD)
  const float* vv   = (const float*)d_in[4];   // v (B,H,NTOT,QD)
  const float* shk  = (const float*)d_in[5];   // single_head_key (B,D,N)
  const float* Wq   = (const float*)d_in[6];   // (128,128)
  const float* MC   = (const float*)d_in[7];   // (128,128)
  const float* eb   = (const float*)d_in[8];   // edge_bias (B,N,N)
  const int*   cn   = (const int*)d_in[9];     // current_node (B,P)

  float* out = (float*)d_out;
  float* ws = (float*)d_ws;
  float* q_ws = ws;                            //   819,200 f
  float* part = ws + 819200;                   // 1,740,800 f (1024*100*17)
  float* mh   = ws + 2560000;                  //   819,200 f
  float* reg  = ws + 3379200;                  // 6,400,000 f shared region:
  unsigned short* m2 = (unsigned short*)reg;   //   mask2 (64*128*1280 ush = 5.24M f)
  float* sc   = reg;                           //   sc overlays m2 (after last m2 read)

  hipLaunchKernelGGL(k_prep, dim3(8592), dim3(256), 0, stream, x, Wq, qf, q_ws, mask, m2);
  hipLaunchKernelGGL(k_mha, dim3(1024), dim3(256), 0, stream, kk, vv, q_ws, m2, part);
  hipLaunchKernelGGL(k_combine, dim3(400), dim3(256), 0, stream, part, MC, mh);
  hipLaunchKernelGGL(k_score2, dim3(1024), dim3(256), 0, stream, mh, shk, sc);
  hipLaunchKernelGGL(k_finsm, dim3(6400), dim3(256), 0, stream, sc, eb, cn, mask, out);
}

// Round 17
// 201.856 us; speedup vs baseline: 1.1037x; 1.1037x over previous
//
#include <hip/hip_runtime.h>
#include <math.h>

#define BB 64
#define PP 100
#define NN 1000
#define DD 128
#define HH 8
#define QDQ 16
#define NTOT 1196
#define QROWS 16
#define LOG2E 1.44269504088896f
#define EXP2(x) __builtin_amdgcn_exp2f(x)

typedef float f2 __attribute__((ext_vector_type(2)));
typedef short s8v __attribute__((ext_vector_type(8)));
typedef float f16v __attribute__((ext_vector_type(16)));

static __device__ __forceinline__ f2 splat2(float v) { f2 r; r.x = v; r.y = v; return r; }
#define PKFMA(a, b, c) __builtin_elementwise_fma((a), (b), (c))

static __device__ __forceinline__ unsigned pkhi(float a, float b) {
  return (__float_as_uint(a) >> 16) | (__float_as_uint(b) & 0xffff0000u);
}
static __device__ __forceinline__ float truncbf(float a) {
  return __uint_as_float(__float_as_uint(a) & 0xffff0000u);
}
#define MFMA32(a, b, c) __builtin_amdgcn_mfma_f32_32x32x16_bf16((a), (b), (c), 0, 0, 0)

// ------- Kernel P: fused {q = q_first + x @ Wq^T} and {mtK key-major table} ---
// blocks 0..399: qcalc (16 bp-rows each); blocks 400..2959: mask transpose
// tiles. mtK[b][j][q] bf16-hi: j = half*640 + local; local<598 -> n=half*598+
// local (n<1000: mask*log2e-20; patch: -20); local>=598 or q>=100: -1e4.
__global__ __launch_bounds__(256) void k_prep(const float* __restrict__ x,
                                              const float* __restrict__ Wq,
                                              const float* __restrict__ qf,
                                              float* __restrict__ qout,
                                              const float* __restrict__ mask,
                                              unsigned short* __restrict__ mtK) {
  __shared__ float sw[128 * 65];
  __shared__ float xs[QROWS * DD];
  int tid = threadIdx.x;

  if (blockIdx.x < 400) {
    int row0 = blockIdx.x * QROWS;
    for (int i = tid; i < QROWS * DD / 4; i += 256)
      ((float4*)xs)[i] = ((const float4*)(x + (size_t)row0 * DD))[i];

    int j = tid & 127, rr = tid >> 7;
    float acc[8];
#pragma unroll
    for (int i = 0; i < 8; ++i) acc[i] = 0.f;

    for (int half = 0; half < 2; ++half) {
      __syncthreads();
      for (int idx = tid; idx < 128 * 64; idx += 256) {
        int jj = idx >> 6, dl = idx & 63;
        sw[jj * 65 + dl] = Wq[jj * DD + half * 64 + dl];
      }
      __syncthreads();
#pragma unroll
      for (int ri = 0; ri < 8; ++ri) {
        int r = 2 * ri + rr;
        float a = acc[ri];
#pragma unroll 16
        for (int dl = 0; dl < 64; ++dl)
          a += xs[r * DD + half * 64 + dl] * sw[j * 65 + dl];
        acc[ri] = a;
      }
    }
#pragma unroll
    for (int ri = 0; ri < 8; ++ri) {
      int bp = row0 + 2 * ri + rr;
      int b = bp / PP, p = bp % PP;
      int h = j >> 4, qd = j & 15;
      size_t qi = ((size_t)(b * HH + h) * PP + p) * QDQ + qd;
      qout[qi] = acc[ri] + qf[qi];
    }
  } else {
    // mask -> mtK[b][j][q] via 64x64 LDS tile transpose (coalesced both sides)
    float (*tile)[65] = (float(*)[65])sw;
    int t2 = blockIdx.x - 400;          // 0..2559
    int b = t2 / 40, rem = t2 % 40;
    int jt = rem % 20, qt2 = rem / 20;  // j-tile 0..19, q-tile 0..1
    int tx = tid & 63, ty = tid >> 6;
    int j0 = jt * 64, q0 = qt2 * 64;
#pragma unroll
    for (int r = ty; r < 64; r += 4) {
      int q = q0 + r, j = j0 + tx;
      int half = j >= 640 ? 1 : 0;
      int local = j - half * 640;
      float val;
      if (q >= PP || local >= 598) {
        val = -1e4f;
      } else {
        int n = half * 598 + local;
        val = (n < NN) ? mask[((size_t)b * PP + q) * NN + n] * LOG2E - 20.f : -20.f;
      }
      tile[r][tx] = val;
    }
    __syncthreads();
#pragma unroll
    for (int r = ty; r < 64; r += 4) {
      int j = j0 + r, q = q0 + tx;
      mtK[((size_t)b * 1280 + j) * 128 + q] =
          (unsigned short)(__float_as_uint(tile[tx][r]) >> 16);
    }
  }
}

// ---------------- Kernel B: MFMA MHA partial (split-bf16, swapped QK^T) -------
// grid = 1024 (XCD-swizzled: 512 bh * 2 halves); block = 256 (4 waves).
// v5 (vs r15): mask C-init reads are key-major coalesced (mtK[b][j][q], lanes
// read contiguous q). All staging/strides/shuffles/math r15-identical.
__global__ __launch_bounds__(256) void k_mha(const float* __restrict__ kk,
                                             const float* __restrict__ vv,
                                             const float* __restrict__ qws,
                                             const unsigned short* __restrict__ mtK,
                                             float* __restrict__ part) {
  int bid = blockIdx.x;
  int swz = (bid & 7) * 128 + (bid >> 3);
  int bh = swz >> 1, half = swz & 1;
  int b = bh >> 3;
  int tid = threadIdx.x;
  int w = tid >> 6, lane = tid & 63;
  int L = lane >> 5, ln = lane & 31;
  bool lo = (L == 0);

  __shared__ __align__(16) char pool[27264];
  char* KspB = pool;                 // [128][80B]: hi 32B | lo 32B | pad 16B
  char* VThB = pool + 10240;         // ushort [16][136] : V^T hi
  char* VTlB = pool + 14592;         // ushort [16][136] : V^T lo
  char* QhB  = pool + 18944;         // ushort [128][16]
  char* QlB  = pool + 23040;

  // ---- stage Q (scaled, split) ----
  {
    const float* qrow = qws + (size_t)bh * (PP * QDQ);
    for (int i = tid; i < 128 * 16; i += 256) {
      int p = i >> 4, qd = i & 15;
      float v = (p < PP) ? qrow[p * QDQ + qd] * (0.25f * LOG2E) : 0.f;
      ((unsigned short*)QhB)[i] = (unsigned short)(__float_as_uint(v) >> 16);
      float rl = v - truncbf(v);
      ((unsigned short*)QlB)[i] = (unsigned short)(__float_as_uint(rl) >> 16);
    }
  }

  const float4* kf4 = (const float4*)kk + (size_t)bh * NTOT * 4;
  const float4* vf4 = (const float4*)vv + (size_t)bh * NTOT * 4;

  f16v Oacc[4];
  float lacc[4];
#pragma unroll
  for (int qt = 0; qt < 4; ++qt) {
    lacc[qt] = 0.f;
#pragma unroll
    for (int r = 0; r < 16; ++r) Oacc[qt][r] = 0.f;
  }
  s8v QhF[4], QlF[4];

  for (int c = 0; c < 5; ++c) {
    __syncthreads();
    // ---- stage 128 keys ----
#pragma unroll
    for (int rep = 0; rep < 2; ++rep) {
      int f = tid + rep * 256;
      int key_l = f >> 2, qd0 = (f & 3) << 2;
      int j = c * 128 + key_l;
      int jc = j < 598 ? j : 597;
      size_t gidx = (size_t)(half * 598 + jc) * 4 + (qd0 >> 2);
      float4 k4 = kf4[gidx];
      unsigned kh01 = pkhi(k4.x, k4.y), kh23 = pkhi(k4.z, k4.w);
      float r0 = k4.x - truncbf(k4.x), r1 = k4.y - truncbf(k4.y);
      float r2 = k4.z - truncbf(k4.z), r3 = k4.w - truncbf(k4.w);
      unsigned kl01 = pkhi(r0, r1), kl23 = pkhi(r2, r3);
      *(uint2*)(KspB + key_l * 80 + qd0 * 2) = make_uint2(kh01, kh23);
      *(uint2*)(KspB + key_l * 80 + 32 + qd0 * 2) = make_uint2(kl01, kl23);
      float4 v4 = vf4[gidx];
      float ve0 = v4.x, ve1 = v4.y, ve2 = v4.z, ve3 = v4.w;
      ((unsigned short*)VThB)[(qd0 + 0) * 136 + key_l] = (unsigned short)(__float_as_uint(ve0) >> 16);
      ((unsigned short*)VThB)[(qd0 + 1) * 136 + key_l] = (unsigned short)(__float_as_uint(ve1) >> 16);
      ((unsigned short*)VThB)[(qd0 + 2) * 136 + key_l] = (unsigned short)(__float_as_uint(ve2) >> 16);
      ((unsigned short*)VThB)[(qd0 + 3) * 136 + key_l] = (unsigned short)(__float_as_uint(ve3) >> 16);
      float w0 = ve0 - truncbf(ve0), w1 = ve1 - truncbf(ve1);
      float w2 = ve2 - truncbf(ve2), w3 = ve3 - truncbf(ve3);
      ((unsigned short*)VTlB)[(qd0 + 0) * 136 + key_l] = (unsigned short)(__float_as_uint(w0) >> 16);
      ((unsigned short*)VTlB)[(qd0 + 1) * 136 + key_l] = (unsigned short)(__float_as_uint(w1) >> 16);
      ((unsigned short*)VTlB)[(qd0 + 2) * 136 + key_l] = (unsigned short)(__float_as_uint(w2) >> 16);
      ((unsigned short*)VTlB)[(qd0 + 3) * 136 + key_l] = (unsigned short)(__float_as_uint(w3) >> 16);
    }
    __syncthreads();
    if (c == 0) {
#pragma unroll
      for (int qt = 0; qt < 4; ++qt) {
        int qr = qt * 32 + ln;
        QhF[qt] = *(const s8v*)(QhB + qr * 32 + L * 16);
        QlF[qt] = *(const s8v*)(QlB + qr * 32 + L * 16);
      }
    }
    // ---- compute this wave's 32-key tile ----
    int ktb = w * 32;
    s8v KhF = *(const s8v*)(KspB + (ktb + ln) * 80 + L * 16);
    s8v KlF = *(const s8v*)(KspB + (ktb + ln) * 80 + 32 + L * 16);
    int vr = ln & 15;
    s8v VhS0 = *(const s8v*)(VThB + vr * 272 + (ktb + L * 8) * 2);
    s8v VhS1 = *(const s8v*)(VThB + vr * 272 + (ktb + 16 + L * 8) * 2);
    s8v VlS0 = *(const s8v*)(VTlB + vr * 272 + (ktb + L * 8) * 2);
    s8v VlS1 = *(const s8v*)(VTlB + vr * 272 + (ktb + 16 + L * 8) * 2);
    // key-major mask base: j = half*640 + c*128 + ktb + 4L (+8g+e); lane reads q
    const unsigned short* mb0 =
        mtK + ((size_t)b * 1280 + half * 640 + c * 128 + ktb + 4 * L) * 128 + ln;
#pragma unroll
    for (int qt = 0; qt < 4; ++qt) {
      const unsigned short* mq = mb0 + qt * 32;
      f16v acc;
#pragma unroll
      for (int g = 0; g < 4; ++g) {
#pragma unroll
        for (int e = 0; e < 4; ++e)
          acc[g * 4 + e] = __uint_as_float((unsigned)mq[(size_t)(8 * g + e) * 128] << 16);
      }
      acc = MFMA32(KhF, QhF[qt], acc);
      acc = MFMA32(KhF, QlF[qt], acc);
      acc = MFMA32(KlF, QhF[qt], acc);
      float p[16];
      float ls = 0.f;
#pragma unroll
      for (int r = 0; r < 16; ++r) { p[r] = EXP2(acc[r]); ls += p[r]; }
      lacc[qt] += ls;
#pragma unroll
      for (int s = 0; s < 2; ++s) {
        unsigned a0 = pkhi(p[8 * s + 0], p[8 * s + 1]), a1 = pkhi(p[8 * s + 2], p[8 * s + 3]);
        unsigned b0 = pkhi(p[8 * s + 4], p[8 * s + 5]), b1 = pkhi(p[8 * s + 6], p[8 * s + 7]);
        unsigned m0 = lo ? b0 : a0;          // single-shuffle half-exchange
        unsigned m1 = lo ? b1 : a1;
        unsigned s0 = __shfl_xor(m0, 32);
        unsigned s1 = __shfl_xor(m1, 32);
        uint4 phu = make_uint4(lo ? a0 : s0, lo ? a1 : s1, lo ? s0 : b0, lo ? s1 : b1);
        float t0 = p[8 * s + 0] - truncbf(p[8 * s + 0]), t1 = p[8 * s + 1] - truncbf(p[8 * s + 1]);
        float t2 = p[8 * s + 2] - truncbf(p[8 * s + 2]), t3 = p[8 * s + 3] - truncbf(p[8 * s + 3]);
        float t4 = p[8 * s + 4] - truncbf(p[8 * s + 4]), t5 = p[8 * s + 5] - truncbf(p[8 * s + 5]);
        float t6 = p[8 * s + 6] - truncbf(p[8 * s + 6]), t7 = p[8 * s + 7] - truncbf(p[8 * s + 7]);
        unsigned c0 = pkhi(t0, t1), c1 = pkhi(t2, t3);
        unsigned e0 = pkhi(t4, t5), e1 = pkhi(t6, t7);
        unsigned n0 = lo ? e0 : c0;
        unsigned n1 = lo ? e1 : c1;
        unsigned u0 = __shfl_xor(n0, 32);
        unsigned u1 = __shfl_xor(n1, 32);
        uint4 plu = make_uint4(lo ? c0 : u0, lo ? c1 : u1, lo ? u0 : e0, lo ? u1 : e1);
        s8v APh = *(s8v*)&phu;
        s8v APl = *(s8v*)&plu;
        s8v Vh = s ? VhS1 : VhS0;
        s8v Vl = s ? VlS1 : VlS0;
        Oacc[qt] = MFMA32(APh, Vh, Oacc[qt]);
        Oacc[qt] = MFMA32(APh, Vl, Oacc[qt]);
        Oacc[qt] = MFMA32(APl, Vh, Oacc[qt]);
      }
    }
  }

  // ---- merge 4 waves -> part records [q][17] (unnormalized A + l) ----
  float lf[4];
#pragma unroll
  for (int qt = 0; qt < 4; ++qt) lf[qt] = lacc[qt] + __shfl_xor(lacc[qt], 32);

  __syncthreads();
  float* marea = (float*)pool;                 // [4][100][16]
  float* larea = (float*)(pool + 25600);       // [4][100]
  if (ln < 16) {
#pragma unroll
    for (int qt = 0; qt < 4; ++qt) {
#pragma unroll
      for (int r = 0; r < 16; ++r) {
        int q = qt * 32 + (r & 3) + 8 * (r >> 2) + 4 * L;
        if (q < PP) marea[(w * PP + q) * 16 + ln] = Oacc[qt][r];
      }
    }
  }
  if (lane < 32) {
#pragma unroll
    for (int qt = 0; qt < 4; ++qt) {
      int q = qt * 32 + ln;
      if (q < PP) larea[w * PP + q] = lf[qt];
    }
  }
  __syncthreads();
  for (int idx = tid; idx < PP * 17; idx += 256) {
    int q = idx / 17, e = idx % 17;
    float sv;
    if (e < 16)
      sv = marea[(0 * PP + q) * 16 + e] + marea[(1 * PP + q) * 16 + e]
         + marea[(2 * PP + q) * 16 + e] + marea[(3 * PP + q) * 16 + e];
    else
      sv = larea[0 * PP + q] + larea[1 * PP + q] + larea[2 * PP + q] + larea[3 * PP + q];
    part[((size_t)swz * PP + q) * 17 + e] = sv;
  }
}

// ---------------- Kernel C: merge 2 halves (sum) + mh_combine (LDS GEMM) ------
__global__ __launch_bounds__(256) void k_combine(const float* __restrict__ part,
                                                 const float* __restrict__ MC,
                                                 float* __restrict__ mh) {
  __shared__ float sw[128 * 65];
  __shared__ float oc[QROWS * DD];
  int tid = threadIdx.x;
  int row0 = blockIdx.x * QROWS;

  for (int i = tid; i < QROWS * DD; i += 256) {
    int r = i >> 7, t = i & 127;
    int bp = row0 + r, b = bp / PP, p = bp % PP;
    int qd = t & 15, h = t >> 4;
    int bh = b * HH + h;
    const float* r0 = part + (((size_t)(bh * 2 + 0)) * PP + p) * 17;
    const float* r1 = part + (((size_t)(bh * 2 + 1)) * PP + p) * 17;
    float A = r0[qd] + r1[qd];
    float L = r0[16] + r1[16];
    oc[i] = A / L;
  }

  int j = tid & 127, rr = tid >> 7;
  float acc[8];
#pragma unroll
  for (int i = 0; i < 8; ++i) acc[i] = 0.f;

  for (int half = 0; half < 2; ++half) {
    __syncthreads();
    for (int idx = tid; idx < 128 * 64; idx += 256) {
      int jj = idx >> 6, dl = idx & 63;
      sw[jj * 65 + dl] = MC[jj * DD + half * 64 + dl];
    }
    __syncthreads();
#pragma unroll
    for (int ri = 0; ri < 8; ++ri) {
      int r = 2 * ri + rr;
      float a = acc[ri];
#pragma unroll 16
      for (int dl = 0; dl < 64; ++dl)
        a += oc[r * DD + half * 64 + dl] * sw[j * 65 + dl];
      acc[ri] = a;
    }
  }
#pragma unroll
  for (int ri = 0; ri < 8; ++ri) {
    int bp = row0 + 2 * ri + rr;
    mh[(size_t)bp * DD + j] = acc[ri];
  }
}

// ------- Kernel D: score2 (packed f32: two n-columns per accumulator) --------
__global__ __launch_bounds__(256) void k_score2(const float* __restrict__ mh,
                                                const float* __restrict__ shk,
                                                float* __restrict__ sc) {
  int bid = blockIdx.x;
  int swz = (bid & 7) * 128 + (bid >> 3);
  int b = swz >> 4, nt = swz & 15;
  int tid = threadIdx.x; int nl = tid & 31, pg = tid >> 5;
  __shared__ float A[PP * 132];
  for (int idx = tid; idx < PP * DD; idx += 256)
    A[(idx >> 7) * 132 + (idx & 127)] = mh[(size_t)b * PP * DD + idx];
  __syncthreads();

  int na = nt * 64 + nl, nb2 = na + 32;
  int nca = na < NN ? na : NN - 1, ncb = nb2 < NN ? nb2 : NN - 1;
  const float* S = shk + (size_t)b * DD * NN;
  f2 accv[13];
#pragma unroll
  for (int i = 0; i < 13; ++i) accv[i] = splat2(0.f);

  for (int d = 0; d < DD; d += 4) {
    f2 s0, s1, s2, s3;
    s0.x = S[(size_t)(d + 0) * NN + nca]; s0.y = S[(size_t)(d + 0) * NN + ncb];
    s1.x = S[(size_t)(d + 1) * NN + nca]; s1.y = S[(size_t)(d + 1) * NN + ncb];
    s2.x = S[(size_t)(d + 2) * NN + nca]; s2.y = S[(size_t)(d + 2) * NN + ncb];
    s3.x = S[(size_t)(d + 3) * NN + nca]; s3.y = S[(size_t)(d + 3) * NN + ncb];
#pragma unroll
    for (int i = 0; i < 13; ++i) {
      int p = pg + (i << 3);
      if (p < PP) {
        const float4 a4 = *(const float4*)&A[p * 132 + d];
        accv[i] = PKFMA(splat2(a4.x), s0, accv[i]);
        accv[i] = PKFMA(splat2(a4.y), s1, accv[i]);
        accv[i] = PKFMA(splat2(a4.z), s2, accv[i]);
        accv[i] = PKFMA(splat2(a4.w), s3, accv[i]);
      }
    }
  }
#pragma unroll
  for (int i = 0; i < 13; ++i) {
    int p = pg + (i << 3);
    if (p < PP) {
      size_t base = ((size_t)b * PP + p) * NN;
      if (na < NN) sc[base + na] = accv[i].x;
      if (nb2 < NN) sc[base + nb2] = accv[i].y;
    }
  }
}

// ------- Kernel E: tanh clip + edge bias + mask + row softmax (no max pass) ---
__global__ __launch_bounds__(256) void k_finsm(const float* __restrict__ sc,
                                               const float* __restrict__ eb,
                                               const int* __restrict__ cn,
                                               const float* __restrict__ mask,
                                               float* __restrict__ out) {
  int bid = blockIdx.x;
  int bp = (bid & 7) * 800 + (bid >> 3);
  int b = bp / PP;
  int t = threadIdx.x;
  int node = cn[bp];
  const float* scp = sc + (size_t)bp * NN;
  const float* ebp = eb + ((size_t)b * NN + node) * NN;
  const float* mp = mask + (size_t)bp * NN;
  const float inv_sqrtD = 0.08838834764831845f;

  float vals[4];
  float s = 0.f;
#pragma unroll
  for (int i = 0; i < 4; ++i) {
    int n = t + (i << 8);
    if (n < NN) {
      float z = scp[n] * inv_sqrtD;
      float e = EXP2(2.f * LOG2E * z);
      float th10 = 10.f - 20.f * __builtin_amdgcn_rcpf(e + 1.f);
      float lg = th10 + ebp[n] + mp[n];
      float e2 = EXP2(lg * LOG2E);
      vals[i] = e2;
      s += e2;
    } else {
      vals[i] = 0.f;
    }
  }
#pragma unroll
  for (int off = 32; off; off >>= 1) s += __shfl_xor(s, off);
  __shared__ float red[4];
  int w = t >> 6, lane = t & 63;
  if (lane == 0) red[w] = s;
  __syncthreads();
  s = (red[0] + red[1]) + (red[2] + red[3]);
  float inv = 1.f / s;
#pragma unroll
  for (int i = 0; i < 4; ++i) {
    int n = t + (i << 8);
    if (n < NN) out[(size_t)bp * NN + n] = vals[i] * inv;
  }
}

extern "C" void kernel_launch(void* const* d_in, const int* in_sizes, int n_in,
                              void* d_out, int out_size, void* d_ws, size_t ws_size,
                              hipStream_t stream) {
  const float* x    = (const float*)d_in[0];   // encoded_last_node (B,P,D)
  const float* mask = (const float*)d_in[1];   // ninf_mask (B,P,N)
  const float* qf   = (const float*)d_in[2];   // q_first (B,H,P,QD)
  const float* kk   = (const float*)d_in[3];   // k (B,H,NTOT,QD)
  const float* vv   = (const float*)d_in[4];   // v (B,H,NTOT,QD)
  const float* shk  = (const float*)d_in[5];   // single_head_key (B,D,N)
  const float* Wq   = (const float*)d_in[6];   // (128,128)
  const float* MC   = (const float*)d_in[7];   // (128,128)
  const float* eb   = (const float*)d_in[8];   // edge_bias (B,N,N)
  const int*   cn   = (const int*)d_in[9];     // current_node (B,P)

  float* out = (float*)d_out;
  float* ws = (float*)d_ws;
  float* q_ws = ws;                            //   819,200 f
  float* part = ws + 819200;                   // 1,740,800 f (1024*100*17)
  float* mh   = ws + 2560000;                  //   819,200 f
  float* reg  = ws + 3379200;                  // 6,400,000 f shared region:
  unsigned short* mtK = (unsigned short*)reg;  //   mtK (64*1280*128 ush = 5.24M f)
  float* sc   = reg;                           //   sc overlays mtK (after last read)

  hipLaunchKernelGGL(k_prep, dim3(2960), dim3(256), 0, stream, x, Wq, qf, q_ws, mask, mtK);
  hipLaunchKernelGGL(k_mha, dim3(1024), dim3(256), 0, stream, kk, vv, q_ws, mtK, part);
  hipLaunchKernelGGL(k_combine, dim3(400), dim3(256), 0, stream, part, MC, mh);
  hipLaunchKernelGGL(k_score2, dim3(1024), dim3(256), 0, stream, mh, shk, sc);
  hipLaunchKernelGGL(k_finsm, dim3(6400), dim3(256), 0, stream, sc, eb, cn, mask, out);
}

// Round 18
// 190.454 us; speedup vs baseline: 1.1698x; 1.0599x over previous
//
#include <hip/hip_runtime.h>
#include <math.h>

#define BB 64
#define PP 100
#define NN 1000
#define DD 128
#define HH 8
#define QDQ 16
#define NTOT 1196
#define QROWS 16
#define LOG2E 1.44269504088896f
#define EXP2(x) __builtin_amdgcn_exp2f(x)

typedef float f2 __attribute__((ext_vector_type(2)));
typedef short s8v __attribute__((ext_vector_type(8)));
typedef float f16v __attribute__((ext_vector_type(16)));

static __device__ __forceinline__ f2 splat2(float v) { f2 r; r.x = v; r.y = v; return r; }
#define PKFMA(a, b, c) __builtin_elementwise_fma((a), (b), (c))

static __device__ __forceinline__ unsigned pkhi(float a, float b) {
  return (__float_as_uint(a) >> 16) | (__float_as_uint(b) & 0xffff0000u);
}
static __device__ __forceinline__ float truncbf(float a) {
  return __uint_as_float(__float_as_uint(a) & 0xffff0000u);
}
#define MFMA32(a, b, c) __builtin_amdgcn_mfma_f32_32x32x16_bf16((a), (b), (c), 0, 0, 0)

// ------- Kernel P: fused {q = q_first + x @ Wq^T} and {mask2 bf16 table} ------
// blocks 0..399: qcalc (16 bp-rows each); blocks 400..8591: mask2 rows (b,q).
__global__ __launch_bounds__(256) void k_prep(const float* __restrict__ x,
                                              const float* __restrict__ Wq,
                                              const float* __restrict__ qf,
                                              float* __restrict__ qout,
                                              const float* __restrict__ mask,
                                              unsigned short* __restrict__ m2) {
  __shared__ float sw[128 * 65];
  __shared__ float xs[QROWS * DD];
  int tid = threadIdx.x;

  if (blockIdx.x < 400) {
    int row0 = blockIdx.x * QROWS;
    for (int i = tid; i < QROWS * DD / 4; i += 256)
      ((float4*)xs)[i] = ((const float4*)(x + (size_t)row0 * DD))[i];

    int j = tid & 127, rr = tid >> 7;
    float acc[8];
#pragma unroll
    for (int i = 0; i < 8; ++i) acc[i] = 0.f;

    for (int half = 0; half < 2; ++half) {
      __syncthreads();
      for (int idx = tid; idx < 128 * 64; idx += 256) {
        int jj = idx >> 6, dl = idx & 63;
        sw[jj * 65 + dl] = Wq[jj * DD + half * 64 + dl];
      }
      __syncthreads();
#pragma unroll
      for (int ri = 0; ri < 8; ++ri) {
        int r = 2 * ri + rr;
        float a = acc[ri];
#pragma unroll 16
        for (int dl = 0; dl < 64; ++dl)
          a += xs[r * DD + half * 64 + dl] * sw[j * 65 + dl];
        acc[ri] = a;
      }
    }
#pragma unroll
    for (int ri = 0; ri < 8; ++ri) {
      int bp = row0 + 2 * ri + rr;
      int b = bp / PP, p = bp % PP;
      int h = j >> 4, qd = j & 15;
      size_t qi = ((size_t)(b * HH + h) * PP + p) * QDQ + qd;
      qout[qi] = acc[ri] + qf[qi];
    }
  } else {
    int t2 = blockIdx.x - 400;
    int b = t2 >> 7, q = t2 & 127;
    unsigned short* dst = m2 + (size_t)(b * 128 + q) * 1280;
    const float* srow = mask + ((size_t)b * PP + (q < PP ? q : PP - 1)) * NN;
    for (int j = tid; j < 1280; j += 256) {
      int h = j >= 640 ? 1 : 0;
      int jj = j - h * 640;
      float val;
      if (q >= PP || jj >= 598) {
        val = -1e4f;
      } else {
        int n = h * 598 + jj;
        val = (n < NN) ? srow[n] * LOG2E - 20.f : -20.f;
      }
      dst[j] = (unsigned short)(__float_as_uint(val) >> 16);
    }
  }
}

// ---------------- Kernel B: MFMA MHA partial (split-bf16, swapped QK^T) -------
// grid = 1024 (XCD-swizzled: 512 bh * 2 halves); block = 256 (4 waves).
// r15-best: K rows 80B stride, V^T 136-ush stride (4-way LDS conflicts),
// single-shuffle half-exchange, inline staging (no reg-prefetch).
__global__ __launch_bounds__(256) void k_mha(const float* __restrict__ kk,
                                             const float* __restrict__ vv,
                                             const float* __restrict__ qws,
                                             const unsigned short* __restrict__ m2,
                                             float* __restrict__ part) {
  int bid = blockIdx.x;
  int swz = (bid & 7) * 128 + (bid >> 3);
  int bh = swz >> 1, half = swz & 1;
  int b = bh >> 3;
  int tid = threadIdx.x;
  int w = tid >> 6, lane = tid & 63;
  int L = lane >> 5, ln = lane & 31;
  bool lo = (L == 0);

  __shared__ __align__(16) char pool[27264];
  char* KspB = pool;                 // [128][80B]: hi 32B | lo 32B | pad 16B
  char* VThB = pool + 10240;         // ushort [16][136] : V^T hi
  char* VTlB = pool + 14592;         // ushort [16][136] : V^T lo
  char* QhB  = pool + 18944;         // ushort [128][16]
  char* QlB  = pool + 23040;

  // ---- stage Q (scaled, split) ----
  {
    const float* qrow = qws + (size_t)bh * (PP * QDQ);
    for (int i = tid; i < 128 * 16; i += 256) {
      int p = i >> 4, qd = i & 15;
      float v = (p < PP) ? qrow[p * QDQ + qd] * (0.25f * LOG2E) : 0.f;
      ((unsigned short*)QhB)[i] = (unsigned short)(__float_as_uint(v) >> 16);
      float rl = v - truncbf(v);
      ((unsigned short*)QlB)[i] = (unsigned short)(__float_as_uint(rl) >> 16);
    }
  }

  const float4* kf4 = (const float4*)kk + (size_t)bh * NTOT * 4;
  const float4* vf4 = (const float4*)vv + (size_t)bh * NTOT * 4;

  f16v Oacc[4];
  float lacc[4];
#pragma unroll
  for (int qt = 0; qt < 4; ++qt) {
    lacc[qt] = 0.f;
#pragma unroll
    for (int r = 0; r < 16; ++r) Oacc[qt][r] = 0.f;
  }
  s8v QhF[4], QlF[4];

  for (int c = 0; c < 5; ++c) {
    __syncthreads();
    // ---- stage 128 keys ----
#pragma unroll
    for (int rep = 0; rep < 2; ++rep) {
      int f = tid + rep * 256;
      int key_l = f >> 2, qd0 = (f & 3) << 2;
      int j = c * 128 + key_l;
      int jc = j < 598 ? j : 597;
      size_t gidx = (size_t)(half * 598 + jc) * 4 + (qd0 >> 2);
      float4 k4 = kf4[gidx];
      unsigned kh01 = pkhi(k4.x, k4.y), kh23 = pkhi(k4.z, k4.w);
      float r0 = k4.x - truncbf(k4.x), r1 = k4.y - truncbf(k4.y);
      float r2 = k4.z - truncbf(k4.z), r3 = k4.w - truncbf(k4.w);
      unsigned kl01 = pkhi(r0, r1), kl23 = pkhi(r2, r3);
      *(uint2*)(KspB + key_l * 80 + qd0 * 2) = make_uint2(kh01, kh23);
      *(uint2*)(KspB + key_l * 80 + 32 + qd0 * 2) = make_uint2(kl01, kl23);
      float4 v4 = vf4[gidx];
      float ve0 = v4.x, ve1 = v4.y, ve2 = v4.z, ve3 = v4.w;
      ((unsigned short*)VThB)[(qd0 + 0) * 136 + key_l] = (unsigned short)(__float_as_uint(ve0) >> 16);
      ((unsigned short*)VThB)[(qd0 + 1) * 136 + key_l] = (unsigned short)(__float_as_uint(ve1) >> 16);
      ((unsigned short*)VThB)[(qd0 + 2) * 136 + key_l] = (unsigned short)(__float_as_uint(ve2) >> 16);
      ((unsigned short*)VThB)[(qd0 + 3) * 136 + key_l] = (unsigned short)(__float_as_uint(ve3) >> 16);
      float w0 = ve0 - truncbf(ve0), w1 = ve1 - truncbf(ve1);
      float w2 = ve2 - truncbf(ve2), w3 = ve3 - truncbf(ve3);
      ((unsigned short*)VTlB)[(qd0 + 0) * 136 + key_l] = (unsigned short)(__float_as_uint(w0) >> 16);
      ((unsigned short*)VTlB)[(qd0 + 1) * 136 + key_l] = (unsigned short)(__float_as_uint(w1) >> 16);
      ((unsigned short*)VTlB)[(qd0 + 2) * 136 + key_l] = (unsigned short)(__float_as_uint(w2) >> 16);
      ((unsigned short*)VTlB)[(qd0 + 3) * 136 + key_l] = (unsigned short)(__float_as_uint(w3) >> 16);
    }
    __syncthreads();
    if (c == 0) {
#pragma unroll
      for (int qt = 0; qt < 4; ++qt) {
        int qr = qt * 32 + ln;
        QhF[qt] = *(const s8v*)(QhB + qr * 32 + L * 16);
        QlF[qt] = *(const s8v*)(QlB + qr * 32 + L * 16);
      }
    }
    // ---- compute this wave's 32-key tile ----
    int ktb = w * 32;
    s8v KhF = *(const s8v*)(KspB + (ktb + ln) * 80 + L * 16);
    s8v KlF = *(const s8v*)(KspB + (ktb + ln) * 80 + 32 + L * 16);
    int vr = ln & 15;
    s8v VhS0 = *(const s8v*)(VThB + vr * 272 + (ktb + L * 8) * 2);
    s8v VhS1 = *(const s8v*)(VThB + vr * 272 + (ktb + 16 + L * 8) * 2);
    s8v VlS0 = *(const s8v*)(VTlB + vr * 272 + (ktb + L * 8) * 2);
    s8v VlS1 = *(const s8v*)(VTlB + vr * 272 + (ktb + 16 + L * 8) * 2);
    size_t mkey = (size_t)half * 640 + c * 128 + ktb + 4 * L;
#pragma unroll
    for (int qt = 0; qt < 4; ++qt) {
      const unsigned short* mrow = m2 + (size_t)(b * 128 + qt * 32 + ln) * 1280 + mkey;
      f16v acc;
#pragma unroll
      for (int g = 0; g < 4; ++g) {
        uint2 md = *(const uint2*)(mrow + g * 8);
        acc[g * 4 + 0] = __uint_as_float(md.x << 16);
        acc[g * 4 + 1] = __uint_as_float(md.x & 0xffff0000u);
        acc[g * 4 + 2] = __uint_as_float(md.y << 16);
        acc[g * 4 + 3] = __uint_as_float(md.y & 0xffff0000u);
      }
      acc = MFMA32(KhF, QhF[qt], acc);
      acc = MFMA32(KhF, QlF[qt], acc);
      acc = MFMA32(KlF, QhF[qt], acc);
      float p[16];
      float ls = 0.f;
#pragma unroll
      for (int r = 0; r < 16; ++r) { p[r] = EXP2(acc[r]); ls += p[r]; }
      lacc[qt] += ls;
#pragma unroll
      for (int s = 0; s < 2; ++s) {
        unsigned a0 = pkhi(p[8 * s + 0], p[8 * s + 1]), a1 = pkhi(p[8 * s + 2], p[8 * s + 3]);
        unsigned b0 = pkhi(p[8 * s + 4], p[8 * s + 5]), b1 = pkhi(p[8 * s + 6], p[8 * s + 7]);
        unsigned m0 = lo ? b0 : a0;          // single-shuffle half-exchange
        unsigned m1 = lo ? b1 : a1;
        unsigned s0 = __shfl_xor(m0, 32);
        unsigned s1 = __shfl_xor(m1, 32);
        uint4 phu = make_uint4(lo ? a0 : s0, lo ? a1 : s1, lo ? s0 : b0, lo ? s1 : b1);
        float t0 = p[8 * s + 0] - truncbf(p[8 * s + 0]), t1 = p[8 * s + 1] - truncbf(p[8 * s + 1]);
        float t2 = p[8 * s + 2] - truncbf(p[8 * s + 2]), t3 = p[8 * s + 3] - truncbf(p[8 * s + 3]);
        float t4 = p[8 * s + 4] - truncbf(p[8 * s + 4]), t5 = p[8 * s + 5] - truncbf(p[8 * s + 5]);
        float t6 = p[8 * s + 6] - truncbf(p[8 * s + 6]), t7 = p[8 * s + 7] - truncbf(p[8 * s + 7]);
        unsigned c0 = pkhi(t0, t1), c1 = pkhi(t2, t3);
        unsigned e0 = pkhi(t4, t5), e1 = pkhi(t6, t7);
        unsigned n0 = lo ? e0 : c0;
        unsigned n1 = lo ? e1 : c1;
        unsigned u0 = __shfl_xor(n0, 32);
        unsigned u1 = __shfl_xor(n1, 32);
        uint4 plu = make_uint4(lo ? c0 : u0, lo ? c1 : u1, lo ? u0 : e0, lo ? u1 : e1);
        s8v APh = *(s8v*)&phu;
        s8v APl = *(s8v*)&plu;
        s8v Vh = s ? VhS1 : VhS0;
        s8v Vl = s ? VlS1 : VlS0;
        Oacc[qt] = MFMA32(APh, Vh, Oacc[qt]);
        Oacc[qt] = MFMA32(APh, Vl, Oacc[qt]);
        Oacc[qt] = MFMA32(APl, Vh, Oacc[qt]);
      }
    }
  }

  // ---- merge 4 waves -> part records [q][17] (unnormalized A + l) ----
  float lf[4];
#pragma unroll
  for (int qt = 0; qt < 4; ++qt) lf[qt] = lacc[qt] + __shfl_xor(lacc[qt], 32);

  __syncthreads();
  float* marea = (float*)pool;                 // [4][100][16]
  float* larea = (float*)(pool + 25600);       // [4][100]
  if (ln < 16) {
#pragma unroll
    for (int qt = 0; qt < 4; ++qt) {
#pragma unroll
      for (int r = 0; r < 16; ++r) {
        int q = qt * 32 + (r & 3) + 8 * (r >> 2) + 4 * L;
        if (q < PP) marea[(w * PP + q) * 16 + ln] = Oacc[qt][r];
      }
    }
  }
  if (lane < 32) {
#pragma unroll
    for (int qt = 0; qt < 4; ++qt) {
      int q = qt * 32 + ln;
      if (q < PP) larea[w * PP + q] = lf[qt];
    }
  }
  __syncthreads();
  for (int idx = tid; idx < PP * 17; idx += 256) {
    int q = idx / 17, e = idx % 17;
    float sv;
    if (e < 16)
      sv = marea[(0 * PP + q) * 16 + e] + marea[(1 * PP + q) * 16 + e]
         + marea[(2 * PP + q) * 16 + e] + marea[(3 * PP + q) * 16 + e];
    else
      sv = larea[0 * PP + q] + larea[1 * PP + q] + larea[2 * PP + q] + larea[3 * PP + q];
    part[((size_t)swz * PP + q) * 17 + e] = sv;
  }
}

// ---------------- Kernel C: merge 2 halves (sum) + mh_combine (LDS GEMM) ------
__global__ __launch_bounds__(256) void k_combine(const float* __restrict__ part,
                                                 const float* __restrict__ MC,
                                                 float* __restrict__ mh) {
  __shared__ float sw[128 * 65];
  __shared__ float oc[QROWS * DD];
  int tid = threadIdx.x;
  int row0 = blockIdx.x * QROWS;

  for (int i = tid; i < QROWS * DD; i += 256) {
    int r = i >> 7, t = i & 127;
    int bp = row0 + r, b = bp / PP, p = bp % PP;
    int qd = t & 15, h = t >> 4;
    int bh = b * HH + h;
    const float* r0 = part + (((size_t)(bh * 2 + 0)) * PP + p) * 17;
    const float* r1 = part + (((size_t)(bh * 2 + 1)) * PP + p) * 17;
    float A = r0[qd] + r1[qd];
    float L = r0[16] + r1[16];
    oc[i] = A / L;
  }

  int j = tid & 127, rr = tid >> 7;
  float acc[8];
#pragma unroll
  for (int i = 0; i < 8; ++i) acc[i] = 0.f;

  for (int half = 0; half < 2; ++half) {
    __syncthreads();
    for (int idx = tid; idx < 128 * 64; idx += 256) {
      int jj = idx >> 6, dl = idx & 63;
      sw[jj * 65 + dl] = MC[jj * DD + half * 64 + dl];
    }
    __syncthreads();
#pragma unroll
    for (int ri = 0; ri < 8; ++ri) {
      int r = 2 * ri + rr;
      float a = acc[ri];
#pragma unroll 16
      for (int dl = 0; dl < 64; ++dl)
        a += oc[r * DD + half * 64 + dl] * sw[j * 65 + dl];
      acc[ri] = a;
    }
  }
#pragma unroll
  for (int ri = 0; ri < 8; ++ri) {
    int bp = row0 + 2 * ri + rr;
    mh[(size_t)bp * DD + j] = acc[ri];
  }
}

// ------- Kernel D: score2 (packed f32: two n-columns per accumulator) --------
__global__ __launch_bounds__(256) void k_score2(const float* __restrict__ mh,
                                                const float* __restrict__ shk,
                                                float* __restrict__ sc) {
  int bid = blockIdx.x;
  int swz = (bid & 7) * 128 + (bid >> 3);
  int b = swz >> 4, nt = swz & 15;
  int tid = threadIdx.x; int nl = tid & 31, pg = tid >> 5;
  __shared__ float A[PP * 132];
  for (int idx = tid; idx < PP * DD; idx += 256)
    A[(idx >> 7) * 132 + (idx & 127)] = mh[(size_t)b * PP * DD + idx];
  __syncthreads();

  int na = nt * 64 + nl, nb2 = na + 32;
  int nca = na < NN ? na : NN - 1, ncb = nb2 < NN ? nb2 : NN - 1;
  const float* S = shk + (size_t)b * DD * NN;
  f2 accv[13];
#pragma unroll
  for (int i = 0; i < 13; ++i) accv[i] = splat2(0.f);

  for (int d = 0; d < DD; d += 4) {
    f2 s0, s1, s2, s3;
    s0.x = S[(size_t)(d + 0) * NN + nca]; s0.y = S[(size_t)(d + 0) * NN + ncb];
    s1.x = S[(size_t)(d + 1) * NN + nca]; s1.y = S[(size_t)(d + 1) * NN + ncb];
    s2.x = S[(size_t)(d + 2) * NN + nca]; s2.y = S[(size_t)(d + 2) * NN + ncb];
    s3.x = S[(size_t)(d + 3) * NN + nca]; s3.y = S[(size_t)(d + 3) * NN + ncb];
#pragma unroll
    for (int i = 0; i < 13; ++i) {
      int p = pg + (i << 3);
      if (p < PP) {
        const float4 a4 = *(const float4*)&A[p * 132 + d];
        accv[i] = PKFMA(splat2(a4.x), s0, accv[i]);
        accv[i] = PKFMA(splat2(a4.y), s1, accv[i]);
        accv[i] = PKFMA(splat2(a4.z), s2, accv[i]);
        accv[i] = PKFMA(splat2(a4.w), s3, accv[i]);
      }
    }
  }
#pragma unroll
  for (int i = 0; i < 13; ++i) {
    int p = pg + (i << 3);
    if (p < PP) {
      size_t base = ((size_t)b * PP + p) * NN;
      if (na < NN) sc[base + na] = accv[i].x;
      if (nb2 < NN) sc[base + nb2] = accv[i].y;
    }
  }
}

// ------- Kernel E: tanh clip + edge bias + mask + row softmax (float4) --------
// 250 lanes x float4 covers N=1000; all row bases 16B-aligned (NN*4=4000).
__global__ __launch_bounds__(256) void k_finsm(const float* __restrict__ sc,
                                               const float* __restrict__ eb,
                                               const int* __restrict__ cn,
                                               const float* __restrict__ mask,
                                               float* __restrict__ out) {
  int bid = blockIdx.x;
  int bp = (bid & 7) * 800 + (bid >> 3);
  int b = bp / PP;
  int t = threadIdx.x;
  int node = cn[bp];
  const float4* scp = (const float4*)(sc + (size_t)bp * NN);
  const float4* ebp = (const float4*)(eb + ((size_t)b * NN + node) * NN);
  const float4* mp  = (const float4*)(mask + (size_t)bp * NN);
  const float inv_sqrtD = 0.08838834764831845f;

  float4 v = make_float4(0.f, 0.f, 0.f, 0.f);
  float s = 0.f;
  if (t < 250) {
    float4 s4 = scp[t];
    float4 e4 = ebp[t];
    float4 m4 = mp[t];
#define FEL(comp) { \
      float z = s4.comp * inv_sqrtD; \
      float e = EXP2(2.f * LOG2E * z); \
      float th10 = 10.f - 20.f * __builtin_amdgcn_rcpf(e + 1.f); \
      float lg = th10 + e4.comp + m4.comp; \
      v.comp = EXP2(lg * LOG2E); }
    FEL(x) FEL(y) FEL(z) FEL(w)
#undef FEL
    s = (v.x + v.y) + (v.z + v.w);
  }
#pragma unroll
  for (int off = 32; off; off >>= 1) s += __shfl_xor(s, off);
  __shared__ float red[4];
  int w = t >> 6, lane = t & 63;
  if (lane == 0) red[w] = s;
  __syncthreads();
  s = (red[0] + red[1]) + (red[2] + red[3]);
  float inv = 1.f / s;
  if (t < 250) {
    float4 o;
    o.x = v.x * inv; o.y = v.y * inv; o.z = v.z * inv; o.w = v.w * inv;
    ((float4*)(out + (size_t)bp * NN))[t] = o;
  }
}

extern "C" void kernel_launch(void* const* d_in, const int* in_sizes, int n_in,
                              void* d_out, int out_size, void* d_ws, size_t ws_size,
                              hipStream_t stream) {
  const float* x    = (const float*)d_in[0];   // encoded_last_node (B,P,D)
  const float* mask = (const float*)d_in[1];   // ninf_mask (B,P,N)
  const float* qf   = (const float*)d_in[2];   // q_first (B,H,P,QD)
  const float* kk   = (const float*)d_in[3];   // k (B,H,NTOT,QD)
  const float* vv   = (const float*)d_in[4];   // v (B,H,NTOT,QD)
  const float* shk  = (const float*)d_in[5];   // single_head_key (B,D,N)
  const float* Wq   = (const float*)d_in[6];   // (128,128)
  const float* MC   = (const float*)d_in[7];   // (128,128)
  const float* eb   = (const float*)d_in[8];   // edge_bias (B,N,N)
  const int*   cn   = (const int*)d_in[9];     // current_node (B,P)

  float* out = (float*)d_out;
  float* ws = (float*)d_ws;
  float* q_ws = ws;                            //   819,200 f
  float* part = ws + 819200;                   // 1,740,800 f (1024*100*17)
  float* mh   = ws + 2560000;                  //   819,200 f
  float* reg  = ws + 3379200;                  // 6,400,000 f shared region:
  unsigned short* m2 = (unsigned short*)reg;   //   mask2 (64*128*1280 ush = 5.24M f)
  float* sc   = reg;                           //   sc overlays m2 (after last m2 read)

  hipLaunchKernelGGL(k_prep, dim3(8592), dim3(256), 0, stream, x, Wq, qf, q_ws, mask, m2);
  hipLaunchKernelGGL(k_mha, dim3(1024), dim3(256), 0, stream, kk, vv, q_ws, m2, part);
  hipLaunchKernelGGL(k_combine, dim3(400), dim3(256), 0, stream, part, MC, mh);
  hipLaunchKernelGGL(k_score2, dim3(1024), dim3(256), 0, stream, mh, shk, sc);
  hipLaunchKernelGGL(k_finsm, dim3(6400), dim3(256), 0, stream, sc, eb, cn, mask, out);
}

// Round 19
// 186.598 us; speedup vs baseline: 1.1940x; 1.0207x over previous
//
#include <hip/hip_runtime.h>
#include <math.h>

#define BB 64
#define PP 100
#define NN 1000
#define DD 128
#define HH 8
#define QDQ 16
#define NTOT 1196
#define QROWS 16
#define LOG2E 1.44269504088896f
#define EXP2(x) __builtin_amdgcn_exp2f(x)

typedef float f2 __attribute__((ext_vector_type(2)));
typedef short s8v __attribute__((ext_vector_type(8)));
typedef float f16v __attribute__((ext_vector_type(16)));

static __device__ __forceinline__ f2 splat2(float v) { f2 r; r.x = v; r.y = v; return r; }
#define PKFMA(a, b, c) __builtin_elementwise_fma((a), (b), (c))

static __device__ __forceinline__ unsigned pkhi(float a, float b) {
  return (__float_as_uint(a) >> 16) | (__float_as_uint(b) & 0xffff0000u);
}
static __device__ __forceinline__ float truncbf(float a) {
  return __uint_as_float(__float_as_uint(a) & 0xffff0000u);
}
#define MFMA32(a, b, c) __builtin_amdgcn_mfma_f32_32x32x16_bf16((a), (b), (c), 0, 0, 0)

// ------- Kernel P: fused {q = q_first + x @ Wq^T} and {mask2 bf16 table} ------
// blocks 0..399: qcalc (16 bp-rows each); blocks 400..8591: mask2 rows (b,q).
__global__ __launch_bounds__(256) void k_prep(const float* __restrict__ x,
                                              const float* __restrict__ Wq,
                                              const float* __restrict__ qf,
                                              float* __restrict__ qout,
                                              const float* __restrict__ mask,
                                              unsigned short* __restrict__ m2) {
  __shared__ float sw[128 * 65];
  __shared__ float xs[QROWS * DD];
  int tid = threadIdx.x;

  if (blockIdx.x < 400) {
    int row0 = blockIdx.x * QROWS;
    for (int i = tid; i < QROWS * DD / 4; i += 256)
      ((float4*)xs)[i] = ((const float4*)(x + (size_t)row0 * DD))[i];

    int j = tid & 127, rr = tid >> 7;
    float acc[8];
#pragma unroll
    for (int i = 0; i < 8; ++i) acc[i] = 0.f;

    for (int half = 0; half < 2; ++half) {
      __syncthreads();
      for (int idx = tid; idx < 128 * 64; idx += 256) {
        int jj = idx >> 6, dl = idx & 63;
        sw[jj * 65 + dl] = Wq[jj * DD + half * 64 + dl];
      }
      __syncthreads();
#pragma unroll
      for (int ri = 0; ri < 8; ++ri) {
        int r = 2 * ri + rr;
        float a = acc[ri];
#pragma unroll 16
        for (int dl = 0; dl < 64; ++dl)
          a += xs[r * DD + half * 64 + dl] * sw[j * 65 + dl];
        acc[ri] = a;
      }
    }
#pragma unroll
    for (int ri = 0; ri < 8; ++ri) {
      int bp = row0 + 2 * ri + rr;
      int b = bp / PP, p = bp % PP;
      int h = j >> 4, qd = j & 15;
      size_t qi = ((size_t)(b * HH + h) * PP + p) * QDQ + qd;
      qout[qi] = acc[ri] + qf[qi];
    }
  } else {
    int t2 = blockIdx.x - 400;
    int b = t2 >> 7, q = t2 & 127;
    unsigned short* dst = m2 + (size_t)(b * 128 + q) * 1280;
    const float* srow = mask + ((size_t)b * PP + (q < PP ? q : PP - 1)) * NN;
    for (int j = tid; j < 1280; j += 256) {
      int h = j >= 640 ? 1 : 0;
      int jj = j - h * 640;
      float val;
      if (q >= PP || jj >= 598) {
        val = -1e4f;
      } else {
        int n = h * 598 + jj;
        val = (n < NN) ? srow[n] * LOG2E - 20.f : -20.f;
      }
      dst[j] = (unsigned short)(__float_as_uint(val) >> 16);
    }
  }
}

// ---------------- Kernel B: MFMA MHA partial (split-bf16, swapped QK^T) -------
// grid = 1024 (XCD-swizzled: 512 bh * 2 halves); block = 256 (4 waves).
// r15-best: K rows 80B stride, V^T 136-ush stride (4-way LDS conflicts),
// single-shuffle half-exchange, inline staging (no reg-prefetch).
__global__ __launch_bounds__(256) void k_mha(const float* __restrict__ kk,
                                             const float* __restrict__ vv,
                                             const float* __restrict__ qws,
                                             const unsigned short* __restrict__ m2,
                                             float* __restrict__ part) {
  int bid = blockIdx.x;
  int swz = (bid & 7) * 128 + (bid >> 3);
  int bh = swz >> 1, half = swz & 1;
  int b = bh >> 3;
  int tid = threadIdx.x;
  int w = tid >> 6, lane = tid & 63;
  int L = lane >> 5, ln = lane & 31;
  bool lo = (L == 0);

  __shared__ __align__(16) char pool[27264];
  char* KspB = pool;                 // [128][80B]: hi 32B | lo 32B | pad 16B
  char* VThB = pool + 10240;         // ushort [16][136] : V^T hi
  char* VTlB = pool + 14592;         // ushort [16][136] : V^T lo
  char* QhB  = pool + 18944;         // ushort [128][16]
  char* QlB  = pool + 23040;

  // ---- stage Q (scaled, split) ----
  {
    const float* qrow = qws + (size_t)bh * (PP * QDQ);
    for (int i = tid; i < 128 * 16; i += 256) {
      int p = i >> 4, qd = i & 15;
      float v = (p < PP) ? qrow[p * QDQ + qd] * (0.25f * LOG2E) : 0.f;
      ((unsigned short*)QhB)[i] = (unsigned short)(__float_as_uint(v) >> 16);
      float rl = v - truncbf(v);
      ((unsigned short*)QlB)[i] = (unsigned short)(__float_as_uint(rl) >> 16);
    }
  }

  const float4* kf4 = (const float4*)kk + (size_t)bh * NTOT * 4;
  const float4* vf4 = (const float4*)vv + (size_t)bh * NTOT * 4;

  f16v Oacc[4];
  float lacc[4];
#pragma unroll
  for (int qt = 0; qt < 4; ++qt) {
    lacc[qt] = 0.f;
#pragma unroll
    for (int r = 0; r < 16; ++r) Oacc[qt][r] = 0.f;
  }
  s8v QhF[4], QlF[4];

  for (int c = 0; c < 5; ++c) {
    __syncthreads();
    // ---- stage 128 keys ----
#pragma unroll
    for (int rep = 0; rep < 2; ++rep) {
      int f = tid + rep * 256;
      int key_l = f >> 2, qd0 = (f & 3) << 2;
      int j = c * 128 + key_l;
      int jc = j < 598 ? j : 597;
      size_t gidx = (size_t)(half * 598 + jc) * 4 + (qd0 >> 2);
      float4 k4 = kf4[gidx];
      unsigned kh01 = pkhi(k4.x, k4.y), kh23 = pkhi(k4.z, k4.w);
      float r0 = k4.x - truncbf(k4.x), r1 = k4.y - truncbf(k4.y);
      float r2 = k4.z - truncbf(k4.z), r3 = k4.w - truncbf(k4.w);
      unsigned kl01 = pkhi(r0, r1), kl23 = pkhi(r2, r3);
      *(uint2*)(KspB + key_l * 80 + qd0 * 2) = make_uint2(kh01, kh23);
      *(uint2*)(KspB + key_l * 80 + 32 + qd0 * 2) = make_uint2(kl01, kl23);
      float4 v4 = vf4[gidx];
      float ve0 = v4.x, ve1 = v4.y, ve2 = v4.z, ve3 = v4.w;
      ((unsigned short*)VThB)[(qd0 + 0) * 136 + key_l] = (unsigned short)(__float_as_uint(ve0) >> 16);
      ((unsigned short*)VThB)[(qd0 + 1) * 136 + key_l] = (unsigned short)(__float_as_uint(ve1) >> 16);
      ((unsigned short*)VThB)[(qd0 + 2) * 136 + key_l] = (unsigned short)(__float_as_uint(ve2) >> 16);
      ((unsigned short*)VThB)[(qd0 + 3) * 136 + key_l] = (unsigned short)(__float_as_uint(ve3) >> 16);
      float w0 = ve0 - truncbf(ve0), w1 = ve1 - truncbf(ve1);
      float w2 = ve2 - truncbf(ve2), w3 = ve3 - truncbf(ve3);
      ((unsigned short*)VTlB)[(qd0 + 0) * 136 + key_l] = (unsigned short)(__float_as_uint(w0) >> 16);
      ((unsigned short*)VTlB)[(qd0 + 1) * 136 + key_l] = (unsigned short)(__float_as_uint(w1) >> 16);
      ((unsigned short*)VTlB)[(qd0 + 2) * 136 + key_l] = (unsigned short)(__float_as_uint(w2) >> 16);
      ((unsigned short*)VTlB)[(qd0 + 3) * 136 + key_l] = (unsigned short)(__float_as_uint(w3) >> 16);
    }
    __syncthreads();
    if (c == 0) {
#pragma unroll
      for (int qt = 0; qt < 4; ++qt) {
        int qr = qt * 32 + ln;
        QhF[qt] = *(const s8v*)(QhB + qr * 32 + L * 16);
        QlF[qt] = *(const s8v*)(QlB + qr * 32 + L * 16);
      }
    }
    // ---- compute this wave's 32-key tile ----
    int ktb = w * 32;
    s8v KhF = *(const s8v*)(KspB + (ktb + ln) * 80 + L * 16);
    s8v KlF = *(const s8v*)(KspB + (ktb + ln) * 80 + 32 + L * 16);
    int vr = ln & 15;
    s8v VhS0 = *(const s8v*)(VThB + vr * 272 + (ktb + L * 8) * 2);
    s8v VhS1 = *(const s8v*)(VThB + vr * 272 + (ktb + 16 + L * 8) * 2);
    s8v VlS0 = *(const s8v*)(VTlB + vr * 272 + (ktb + L * 8) * 2);
    s8v VlS1 = *(const s8v*)(VTlB + vr * 272 + (ktb + 16 + L * 8) * 2);
    size_t mkey = (size_t)half * 640 + c * 128 + ktb + 4 * L;
#pragma unroll
    for (int qt = 0; qt < 4; ++qt) {
      const unsigned short* mrow = m2 + (size_t)(b * 128 + qt * 32 + ln) * 1280 + mkey;
      f16v acc;
#pragma unroll
      for (int g = 0; g < 4; ++g) {
        uint2 md = *(const uint2*)(mrow + g * 8);
        acc[g * 4 + 0] = __uint_as_float(md.x << 16);
        acc[g * 4 + 1] = __uint_as_float(md.x & 0xffff0000u);
        acc[g * 4 + 2] = __uint_as_float(md.y << 16);
        acc[g * 4 + 3] = __uint_as_float(md.y & 0xffff0000u);
      }
      acc = MFMA32(KhF, QhF[qt], acc);
      acc = MFMA32(KhF, QlF[qt], acc);
      acc = MFMA32(KlF, QhF[qt], acc);
      float p[16];
      float ls = 0.f;
#pragma unroll
      for (int r = 0; r < 16; ++r) { p[r] = EXP2(acc[r]); ls += p[r]; }
      lacc[qt] += ls;
#pragma unroll
      for (int s = 0; s < 2; ++s) {
        unsigned a0 = pkhi(p[8 * s + 0], p[8 * s + 1]), a1 = pkhi(p[8 * s + 2], p[8 * s + 3]);
        unsigned b0 = pkhi(p[8 * s + 4], p[8 * s + 5]), b1 = pkhi(p[8 * s + 6], p[8 * s + 7]);
        unsigned m0 = lo ? b0 : a0;          // single-shuffle half-exchange
        unsigned m1 = lo ? b1 : a1;
        unsigned s0 = __shfl_xor(m0, 32);
        unsigned s1 = __shfl_xor(m1, 32);
        uint4 phu = make_uint4(lo ? a0 : s0, lo ? a1 : s1, lo ? s0 : b0, lo ? s1 : b1);
        float t0 = p[8 * s + 0] - truncbf(p[8 * s + 0]), t1 = p[8 * s + 1] - truncbf(p[8 * s + 1]);
        float t2 = p[8 * s + 2] - truncbf(p[8 * s + 2]), t3 = p[8 * s + 3] - truncbf(p[8 * s + 3]);
        float t4 = p[8 * s + 4] - truncbf(p[8 * s + 4]), t5 = p[8 * s + 5] - truncbf(p[8 * s + 5]);
        float t6 = p[8 * s + 6] - truncbf(p[8 * s + 6]), t7 = p[8 * s + 7] - truncbf(p[8 * s + 7]);
        unsigned c0 = pkhi(t0, t1), c1 = pkhi(t2, t3);
        unsigned e0 = pkhi(t4, t5), e1 = pkhi(t6, t7);
        unsigned n0 = lo ? e0 : c0;
        unsigned n1 = lo ? e1 : c1;
        unsigned u0 = __shfl_xor(n0, 32);
        unsigned u1 = __shfl_xor(n1, 32);
        uint4 plu = make_uint4(lo ? c0 : u0, lo ? c1 : u1, lo ? u0 : e0, lo ? u1 : e1);
        s8v APh = *(s8v*)&phu;
        s8v APl = *(s8v*)&plu;
        s8v Vh = s ? VhS1 : VhS0;
        s8v Vl = s ? VlS1 : VlS0;
        Oacc[qt] = MFMA32(APh, Vh, Oacc[qt]);
        Oacc[qt] = MFMA32(APh, Vl, Oacc[qt]);
        Oacc[qt] = MFMA32(APl, Vh, Oacc[qt]);
      }
    }
  }

  // ---- merge 4 waves -> part records [q][17] (unnormalized A + l) ----
  float lf[4];
#pragma unroll
  for (int qt = 0; qt < 4; ++qt) lf[qt] = lacc[qt] + __shfl_xor(lacc[qt], 32);

  __syncthreads();
  float* marea = (float*)pool;                 // [4][100][16]
  float* larea = (float*)(pool + 25600);       // [4][100]
  if (ln < 16) {
#pragma unroll
    for (int qt = 0; qt < 4; ++qt) {
#pragma unroll
      for (int r = 0; r < 16; ++r) {
        int q = qt * 32 + (r & 3) + 8 * (r >> 2) + 4 * L;
        if (q < PP) marea[(w * PP + q) * 16 + ln] = Oacc[qt][r];
      }
    }
  }
  if (lane < 32) {
#pragma unroll
    for (int qt = 0; qt < 4; ++qt) {
      int q = qt * 32 + ln;
      if (q < PP) larea[w * PP + q] = lf[qt];
    }
  }
  __syncthreads();
  for (int idx = tid; idx < PP * 17; idx += 256) {
    int q = idx / 17, e = idx % 17;
    float sv;
    if (e < 16)
      sv = marea[(0 * PP + q) * 16 + e] + marea[(1 * PP + q) * 16 + e]
         + marea[(2 * PP + q) * 16 + e] + marea[(3 * PP + q) * 16 + e];
    else
      sv = larea[0 * PP + q] + larea[1 * PP + q] + larea[2 * PP + q] + larea[3 * PP + q];
    part[((size_t)swz * PP + q) * 17 + e] = sv;
  }
}

// ---------------- Kernel C: merge 2 halves (sum) + mh_combine (LDS GEMM) ------
__global__ __launch_bounds__(256) void k_combine(const float* __restrict__ part,
                                                 const float* __restrict__ MC,
                                                 float* __restrict__ mh) {
  __shared__ float sw[128 * 65];
  __shared__ float oc[QROWS * DD];
  int tid = threadIdx.x;
  int row0 = blockIdx.x * QROWS;

  for (int i = tid; i < QROWS * DD; i += 256) {
    int r = i >> 7, t = i & 127;
    int bp = row0 + r, b = bp / PP, p = bp % PP;
    int qd = t & 15, h = t >> 4;
    int bh = b * HH + h;
    const float* r0 = part + (((size_t)(bh * 2 + 0)) * PP + p) * 17;
    const float* r1 = part + (((size_t)(bh * 2 + 1)) * PP + p) * 17;
    float A = r0[qd] + r1[qd];
    float L = r0[16] + r1[16];
    oc[i] = A / L;
  }

  int j = tid & 127, rr = tid >> 7;
  float acc[8];
#pragma unroll
  for (int i = 0; i < 8; ++i) acc[i] = 0.f;

  for (int half = 0; half < 2; ++half) {
    __syncthreads();
    for (int idx = tid; idx < 128 * 64; idx += 256) {
      int jj = idx >> 6, dl = idx & 63;
      sw[jj * 65 + dl] = MC[jj * DD + half * 64 + dl];
    }
    __syncthreads();
#pragma unroll
    for (int ri = 0; ri < 8; ++ri) {
      int r = 2 * ri + rr;
      float a = acc[ri];
#pragma unroll 16
      for (int dl = 0; dl < 64; ++dl)
        a += oc[r * DD + half * 64 + dl] * sw[j * 65 + dl];
      acc[ri] = a;
    }
  }
#pragma unroll
  for (int ri = 0; ri < 8; ++ri) {
    int bp = row0 + 2 * ri + rr;
    mh[(size_t)bp * DD + j] = acc[ri];
  }
}

// ------- Kernel D: score2 (packed f32: two n-columns per accumulator) --------
__global__ __launch_bounds__(256) void k_score2(const float* __restrict__ mh,
                                                const float* __restrict__ shk,
                                                float* __restrict__ sc) {
  int bid = blockIdx.x;
  int swz = (bid & 7) * 128 + (bid >> 3);
  int b = swz >> 4, nt = swz & 15;
  int tid = threadIdx.x; int nl = tid & 31, pg = tid >> 5;
  __shared__ float A[PP * 132];
  for (int idx = tid; idx < PP * DD; idx += 256)
    A[(idx >> 7) * 132 + (idx & 127)] = mh[(size_t)b * PP * DD + idx];
  __syncthreads();

  int na = nt * 64 + nl, nb2 = na + 32;
  int nca = na < NN ? na : NN - 1, ncb = nb2 < NN ? nb2 : NN - 1;
  const float* S = shk + (size_t)b * DD * NN;
  f2 accv[13];
#pragma unroll
  for (int i = 0; i < 13; ++i) accv[i] = splat2(0.f);

  for (int d = 0; d < DD; d += 4) {
    f2 s0, s1, s2, s3;
    s0.x = S[(size_t)(d + 0) * NN + nca]; s0.y = S[(size_t)(d + 0) * NN + ncb];
    s1.x = S[(size_t)(d + 1) * NN + nca]; s1.y = S[(size_t)(d + 1) * NN + ncb];
    s2.x = S[(size_t)(d + 2) * NN + nca]; s2.y = S[(size_t)(d + 2) * NN + ncb];
    s3.x = S[(size_t)(d + 3) * NN + nca]; s3.y = S[(size_t)(d + 3) * NN + ncb];
#pragma unroll
    for (int i = 0; i < 13; ++i) {
      int p = pg + (i << 3);
      if (p < PP) {
        const float4 a4 = *(const float4*)&A[p * 132 + d];
        accv[i] = PKFMA(splat2(a4.x), s0, accv[i]);
        accv[i] = PKFMA(splat2(a4.y), s1, accv[i]);
        accv[i] = PKFMA(splat2(a4.z), s2, accv[i]);
        accv[i] = PKFMA(splat2(a4.w), s3, accv[i]);
      }
    }
  }
#pragma unroll
  for (int i = 0; i < 13; ++i) {
    int p = pg + (i << 3);
    if (p < PP) {
      size_t base = ((size_t)b * PP + p) * NN;
      if (na < NN) sc[base + na] = accv[i].x;
      if (nb2 < NN) sc[base + nb2] = accv[i].y;
    }
  }
}

// ------- Kernel E: tanh clip + edge bias + mask + row softmax (no max pass) ---
__global__ __launch_bounds__(256) void k_finsm(const float* __restrict__ sc,
                                               const float* __restrict__ eb,
                                               const int* __restrict__ cn,
                                               const float* __restrict__ mask,
                                               float* __restrict__ out) {
  int bid = blockIdx.x;
  int bp = (bid & 7) * 800 + (bid >> 3);
  int b = bp / PP;
  int t = threadIdx.x;
  int node = cn[bp];
  const float* scp = sc + (size_t)bp * NN;
  const float* ebp = eb + ((size_t)b * NN + node) * NN;
  const float* mp = mask + (size_t)bp * NN;
  const float inv_sqrtD = 0.08838834764831845f;

  float vals[4];
  float s = 0.f;
#pragma unroll
  for (int i = 0; i < 4; ++i) {
    int n = t + (i << 8);
    if (n < NN) {
      float z = scp[n] * inv_sqrtD;
      float e = EXP2(2.f * LOG2E * z);
      float th10 = 10.f - 20.f * __builtin_amdgcn_rcpf(e + 1.f);
      float lg = th10 + ebp[n] + mp[n];
      float e2 = EXP2(lg * LOG2E);
      vals[i] = e2;
      s += e2;
    } else {
      vals[i] = 0.f;
    }
  }
#pragma unroll
  for (int off = 32; off; off >>= 1) s += __shfl_xor(s, off);
  __shared__ float red[4];
  int w = t >> 6, lane = t & 63;
  if (lane == 0) red[w] = s;
  __syncthreads();
  s = (red[0] + red[1]) + (red[2] + red[3]);
  float inv = 1.f / s;
#pragma unroll
  for (int i = 0; i < 4; ++i) {
    int n = t + (i << 8);
    if (n < NN) out[(size_t)bp * NN + n] = vals[i] * inv;
  }
}

extern "C" void kernel_launch(void* const* d_in, const int* in_sizes, int n_in,
                              void* d_out, int out_size, void* d_ws, size_t ws_size,
                              hipStream_t stream) {
  const float* x    = (const float*)d_in[0];   // encoded_last_node (B,P,D)
  const float* mask = (const float*)d_in[1];   // ninf_mask (B,P,N)
  const float* qf   = (const float*)d_in[2];   // q_first (B,H,P,QD)
  const float* kk   = (const float*)d_in[3];   // k (B,H,NTOT,QD)
  const float* vv   = (const float*)d_in[4];   // v (B,H,NTOT,QD)
  const float* shk  = (const float*)d_in[5];   // single_head_key (B,D,N)
  const float* Wq   = (const float*)d_in[6];   // (128,128)
  const float* MC   = (const float*)d_in[7];   // (128,128)
  const float* eb   = (const float*)d_in[8];   // edge_bias (B,N,N)
  const int*   cn   = (const int*)d_in[9];     // current_node (B,P)

  float* out = (float*)d_out;
  float* ws = (float*)d_ws;
  float* q_ws = ws;                            //   819,200 f
  float* part = ws + 819200;                   // 1,740,800 f (1024*100*17)
  float* mh   = ws + 2560000;                  //   819,200 f
  float* reg  = ws + 3379200;                  // 6,400,000 f shared region:
  unsigned short* m2 = (unsigned short*)reg;   //   mask2 (64*128*1280 ush = 5.24M f)
  float* sc   = reg;                           //   sc overlays m2 (after last m2 read)

  hipLaunchKernelGGL(k_prep, dim3(8592), dim3(256), 0, stream, x, Wq, qf, q_ws, mask, m2);
  hipLaunchKernelGGL(k_mha, dim3(1024), dim3(256), 0, stream, kk, vv, q_ws, m2, part);
  hipLaunchKernelGGL(k_combine, dim3(400), dim3(256), 0, stream, part, MC, mh);
  hipLaunchKernelGGL(k_score2, dim3(1024), dim3(256), 0, stream, mh, shk, sc);
  hipLaunchKernelGGL(k_finsm, dim3(6400), dim3(256), 0, stream, sc, eb, cn, mask, out);
}

// Round 20
// 183.249 us; speedup vs baseline: 1.2158x; 1.0183x over previous
//
#include <hip/hip_runtime.h>
#include <math.h>

#define BB 64
#define PP 100
#define NN 1000
#define DD 128
#define HH 8
#define QDQ 16
#define NTOT 1196
#define QROWS 16
#define LOG2E 1.44269504088896f
#define EXP2(x) __builtin_amdgcn_exp2f(x)

typedef float f2 __attribute__((ext_vector_type(2)));
typedef short s8v __attribute__((ext_vector_type(8)));
typedef float f16v __attribute__((ext_vector_type(16)));

static __device__ __forceinline__ f2 splat2(float v) { f2 r; r.x = v; r.y = v; return r; }
#define PKFMA(a, b, c) __builtin_elementwise_fma((a), (b), (c))

static __device__ __forceinline__ unsigned pkhi(float a, float b) {
  return (__float_as_uint(a) >> 16) | (__float_as_uint(b) & 0xffff0000u);
}
static __device__ __forceinline__ float truncbf(float a) {
  return __uint_as_float(__float_as_uint(a) & 0xffff0000u);
}
#define MFMA32(a, b, c) __builtin_amdgcn_mfma_f32_32x32x16_bf16((a), (b), (c), 0, 0, 0)

// ------- Kernel P: fused {q = q_first + x @ Wq^T} and {mask2 bf16 table} ------
// blocks 0..399: qcalc (16 bp-rows each); blocks 400..8591: mask2 rows (b,q).
__global__ __launch_bounds__(256) void k_prep(const float* __restrict__ x,
                                              const float* __restrict__ Wq,
                                              const float* __restrict__ qf,
                                              float* __restrict__ qout,
                                              const float* __restrict__ mask,
                                              unsigned short* __restrict__ m2) {
  __shared__ float sw[128 * 65];
  __shared__ float xs[QROWS * DD];
  int tid = threadIdx.x;

  if (blockIdx.x < 400) {
    int row0 = blockIdx.x * QROWS;
    for (int i = tid; i < QROWS * DD / 4; i += 256)
      ((float4*)xs)[i] = ((const float4*)(x + (size_t)row0 * DD))[i];

    int j = tid & 127, rr = tid >> 7;
    float acc[8];
#pragma unroll
    for (int i = 0; i < 8; ++i) acc[i] = 0.f;

    for (int half = 0; half < 2; ++half) {
      __syncthreads();
      for (int idx = tid; idx < 128 * 64; idx += 256) {
        int jj = idx >> 6, dl = idx & 63;
        sw[jj * 65 + dl] = Wq[jj * DD + half * 64 + dl];
      }
      __syncthreads();
#pragma unroll
      for (int ri = 0; ri < 8; ++ri) {
        int r = 2 * ri + rr;
        float a = acc[ri];
#pragma unroll 16
        for (int dl = 0; dl < 64; ++dl)
          a += xs[r * DD + half * 64 + dl] * sw[j * 65 + dl];
        acc[ri] = a;
      }
    }
#pragma unroll
    for (int ri = 0; ri < 8; ++ri) {
      int bp = row0 + 2 * ri + rr;
      int b = bp / PP, p = bp % PP;
      int h = j >> 4, qd = j & 15;
      size_t qi = ((size_t)(b * HH + h) * PP + p) * QDQ + qd;
      qout[qi] = acc[ri] + qf[qi];
    }
  } else {
    int t2 = blockIdx.x - 400;
    int b = t2 >> 7, q = t2 & 127;
    unsigned short* dst = m2 + (size_t)(b * 128 + q) * 1280;
    const float* srow = mask + ((size_t)b * PP + (q < PP ? q : PP - 1)) * NN;
    for (int j = tid; j < 1280; j += 256) {
      int h = j >= 640 ? 1 : 0;
      int jj = j - h * 640;
      float val;
      if (q >= PP || jj >= 598) {
        val = -1e4f;
      } else {
        int n = h * 598 + jj;
        val = (n < NN) ? srow[n] * LOG2E - 20.f : -20.f;
      }
      dst[j] = (unsigned short)(__float_as_uint(val) >> 16);
    }
  }
}

// ---------------- Kernel B: MFMA MHA partial (split-bf16, swapped QK^T) -------
// grid = 1024 (XCD-swizzled: 512 bh * 2 halves); block = 256 (4 waves).
// v6 (vs r15): PV uses truncated-P weights with CONSISTENT l = sum(trunc(p))
// -> drops the APl correction MFMA + its repack/shuffles (numerator and
// denominator use identical weights, so truncation is a valid reweighting).
__global__ __launch_bounds__(256) void k_mha(const float* __restrict__ kk,
                                             const float* __restrict__ vv,
                                             const float* __restrict__ qws,
                                             const unsigned short* __restrict__ m2,
                                             float* __restrict__ part) {
  int bid = blockIdx.x;
  int swz = (bid & 7) * 128 + (bid >> 3);
  int bh = swz >> 1, half = swz & 1;
  int b = bh >> 3;
  int tid = threadIdx.x;
  int w = tid >> 6, lane = tid & 63;
  int L = lane >> 5, ln = lane & 31;
  bool lo = (L == 0);

  __shared__ __align__(16) char pool[27264];
  char* KspB = pool;                 // [128][80B]: hi 32B | lo 32B | pad 16B
  char* VThB = pool + 10240;         // ushort [16][136] : V^T hi
  char* VTlB = pool + 14592;         // ushort [16][136] : V^T lo
  char* QhB  = pool + 18944;         // ushort [128][16]
  char* QlB  = pool + 23040;

  // ---- stage Q (scaled, split) ----
  {
    const float* qrow = qws + (size_t)bh * (PP * QDQ);
    for (int i = tid; i < 128 * 16; i += 256) {
      int p = i >> 4, qd = i & 15;
      float v = (p < PP) ? qrow[p * QDQ + qd] * (0.25f * LOG2E) : 0.f;
      ((unsigned short*)QhB)[i] = (unsigned short)(__float_as_uint(v) >> 16);
      float rl = v - truncbf(v);
      ((unsigned short*)QlB)[i] = (unsigned short)(__float_as_uint(rl) >> 16);
    }
  }

  const float4* kf4 = (const float4*)kk + (size_t)bh * NTOT * 4;
  const float4* vf4 = (const float4*)vv + (size_t)bh * NTOT * 4;

  f16v Oacc[4];
  float lacc[4];
#pragma unroll
  for (int qt = 0; qt < 4; ++qt) {
    lacc[qt] = 0.f;
#pragma unroll
    for (int r = 0; r < 16; ++r) Oacc[qt][r] = 0.f;
  }
  s8v QhF[4], QlF[4];

  for (int c = 0; c < 5; ++c) {
    __syncthreads();
    // ---- stage 128 keys ----
#pragma unroll
    for (int rep = 0; rep < 2; ++rep) {
      int f = tid + rep * 256;
      int key_l = f >> 2, qd0 = (f & 3) << 2;
      int j = c * 128 + key_l;
      int jc = j < 598 ? j : 597;
      size_t gidx = (size_t)(half * 598 + jc) * 4 + (qd0 >> 2);
      float4 k4 = kf4[gidx];
      unsigned kh01 = pkhi(k4.x, k4.y), kh23 = pkhi(k4.z, k4.w);
      float r0 = k4.x - truncbf(k4.x), r1 = k4.y - truncbf(k4.y);
      float r2 = k4.z - truncbf(k4.z), r3 = k4.w - truncbf(k4.w);
      unsigned kl01 = pkhi(r0, r1), kl23 = pkhi(r2, r3);
      *(uint2*)(KspB + key_l * 80 + qd0 * 2) = make_uint2(kh01, kh23);
      *(uint2*)(KspB + key_l * 80 + 32 + qd0 * 2) = make_uint2(kl01, kl23);
      float4 v4 = vf4[gidx];
      float ve0 = v4.x, ve1 = v4.y, ve2 = v4.z, ve3 = v4.w;
      ((unsigned short*)VThB)[(qd0 + 0) * 136 + key_l] = (unsigned short)(__float_as_uint(ve0) >> 16);
      ((unsigned short*)VThB)[(qd0 + 1) * 136 + key_l] = (unsigned short)(__float_as_uint(ve1) >> 16);
      ((unsigned short*)VThB)[(qd0 + 2) * 136 + key_l] = (unsigned short)(__float_as_uint(ve2) >> 16);
      ((unsigned short*)VThB)[(qd0 + 3) * 136 + key_l] = (unsigned short)(__float_as_uint(ve3) >> 16);
      float w0 = ve0 - truncbf(ve0), w1 = ve1 - truncbf(ve1);
      float w2 = ve2 - truncbf(ve2), w3 = ve3 - truncbf(ve3);
      ((unsigned short*)VTlB)[(qd0 + 0) * 136 + key_l] = (unsigned short)(__float_as_uint(w0) >> 16);
      ((unsigned short*)VTlB)[(qd0 + 1) * 136 + key_l] = (unsigned short)(__float_as_uint(w1) >> 16);
      ((unsigned short*)VTlB)[(qd0 + 2) * 136 + key_l] = (unsigned short)(__float_as_uint(w2) >> 16);
      ((unsigned short*)VTlB)[(qd0 + 3) * 136 + key_l] = (unsigned short)(__float_as_uint(w3) >> 16);
    }
    __syncthreads();
    if (c == 0) {
#pragma unroll
      for (int qt = 0; qt < 4; ++qt) {
        int qr = qt * 32 + ln;
        QhF[qt] = *(const s8v*)(QhB + qr * 32 + L * 16);
        QlF[qt] = *(const s8v*)(QlB + qr * 32 + L * 16);
      }
    }
    // ---- compute this wave's 32-key tile ----
    int ktb = w * 32;
    s8v KhF = *(const s8v*)(KspB + (ktb + ln) * 80 + L * 16);
    s8v KlF = *(const s8v*)(KspB + (ktb + ln) * 80 + 32 + L * 16);
    int vr = ln & 15;
    s8v VhS0 = *(const s8v*)(VThB + vr * 272 + (ktb + L * 8) * 2);
    s8v VhS1 = *(const s8v*)(VThB + vr * 272 + (ktb + 16 + L * 8) * 2);
    s8v VlS0 = *(const s8v*)(VTlB + vr * 272 + (ktb + L * 8) * 2);
    s8v VlS1 = *(const s8v*)(VTlB + vr * 272 + (ktb + 16 + L * 8) * 2);
    size_t mkey = (size_t)half * 640 + c * 128 + ktb + 4 * L;
#pragma unroll
    for (int qt = 0; qt < 4; ++qt) {
      const unsigned short* mrow = m2 + (size_t)(b * 128 + qt * 32 + ln) * 1280 + mkey;
      f16v acc;
#pragma unroll
      for (int g = 0; g < 4; ++g) {
        uint2 md = *(const uint2*)(mrow + g * 8);
        acc[g * 4 + 0] = __uint_as_float(md.x << 16);
        acc[g * 4 + 1] = __uint_as_float(md.x & 0xffff0000u);
        acc[g * 4 + 2] = __uint_as_float(md.y << 16);
        acc[g * 4 + 3] = __uint_as_float(md.y & 0xffff0000u);
      }
      acc = MFMA32(KhF, QhF[qt], acc);
      acc = MFMA32(KhF, QlF[qt], acc);
      acc = MFMA32(KlF, QhF[qt], acc);
      float p[16];
      float ls = 0.f;
#pragma unroll
      for (int r = 0; r < 16; ++r) {
        p[r] = EXP2(acc[r]);
        ls += truncbf(p[r]);               // l consistent with truncated weights
      }
      lacc[qt] += ls;
#pragma unroll
      for (int s = 0; s < 2; ++s) {
        unsigned a0 = pkhi(p[8 * s + 0], p[8 * s + 1]), a1 = pkhi(p[8 * s + 2], p[8 * s + 3]);
        unsigned b0 = pkhi(p[8 * s + 4], p[8 * s + 5]), b1 = pkhi(p[8 * s + 6], p[8 * s + 7]);
        unsigned m0 = lo ? b0 : a0;          // single-shuffle half-exchange
        unsigned m1 = lo ? b1 : a1;
        unsigned s0 = __shfl_xor(m0, 32);
        unsigned s1 = __shfl_xor(m1, 32);
        uint4 phu = make_uint4(lo ? a0 : s0, lo ? a1 : s1, lo ? s0 : b0, lo ? s1 : b1);
        s8v APh = *(s8v*)&phu;
        s8v Vh = s ? VhS1 : VhS0;
        s8v Vl = s ? VlS1 : VlS0;
        Oacc[qt] = MFMA32(APh, Vh, Oacc[qt]);
        Oacc[qt] = MFMA32(APh, Vl, Oacc[qt]);
      }
    }
  }

  // ---- merge 4 waves -> part records [q][17] (unnormalized A + l) ----
  float lf[4];
#pragma unroll
  for (int qt = 0; qt < 4; ++qt) lf[qt] = lacc[qt] + __shfl_xor(lacc[qt], 32);

  __syncthreads();
  float* marea = (float*)pool;                 // [4][100][16]
  float* larea = (float*)(pool + 25600);       // [4][100]
  if (ln < 16) {
#pragma unroll
    for (int qt = 0; qt < 4; ++qt) {
#pragma unroll
      for (int r = 0; r < 16; ++r) {
        int q = qt * 32 + (r & 3) + 8 * (r >> 2) + 4 * L;
        if (q < PP) marea[(w * PP + q) * 16 + ln] = Oacc[qt][r];
      }
    }
  }
  if (lane < 32) {
#pragma unroll
    for (int qt = 0; qt < 4; ++qt) {
      int q = qt * 32 + ln;
      if (q < PP) larea[w * PP + q] = lf[qt];
    }
  }
  __syncthreads();
  for (int idx = tid; idx < PP * 17; idx += 256) {
    int q = idx / 17, e = idx % 17;
    float sv;
    if (e < 16)
      sv = marea[(0 * PP + q) * 16 + e] + marea[(1 * PP + q) * 16 + e]
         + marea[(2 * PP + q) * 16 + e] + marea[(3 * PP + q) * 16 + e];
    else
      sv = larea[0 * PP + q] + larea[1 * PP + q] + larea[2 * PP + q] + larea[3 * PP + q];
    part[((size_t)swz * PP + q) * 17 + e] = sv;
  }
}

// ---------------- Kernel C: merge 2 halves (sum) + mh_combine (LDS GEMM) ------
__global__ __launch_bounds__(256) void k_combine(const float* __restrict__ part,
                                                 const float* __restrict__ MC,
                                                 float* __restrict__ mh) {
  __shared__ float sw[128 * 65];
  __shared__ float oc[QROWS * DD];
  int tid = threadIdx.x;
  int row0 = blockIdx.x * QROWS;

  for (int i = tid; i < QROWS * DD; i += 256) {
    int r = i >> 7, t = i & 127;
    int bp = row0 + r, b = bp / PP, p = bp % PP;
    int qd = t & 15, h = t >> 4;
    int bh = b * HH + h;
    const float* r0 = part + (((size_t)(bh * 2 + 0)) * PP + p) * 17;
    const float* r1 = part + (((size_t)(bh * 2 + 1)) * PP + p) * 17;
    float A = r0[qd] + r1[qd];
    float L = r0[16] + r1[16];
    oc[i] = A / L;
  }

  int j = tid & 127, rr = tid >> 7;
  float acc[8];
#pragma unroll
  for (int i = 0; i < 8; ++i) acc[i] = 0.f;

  for (int half = 0; half < 2; ++half) {
    __syncthreads();
    for (int idx = tid; idx < 128 * 64; idx += 256) {
      int jj = idx >> 6, dl = idx & 63;
      sw[jj * 65 + dl] = MC[jj * DD + half * 64 + dl];
    }
    __syncthreads();
#pragma unroll
    for (int ri = 0; ri < 8; ++ri) {
      int r = 2 * ri + rr;
      float a = acc[ri];
#pragma unroll 16
      for (int dl = 0; dl < 64; ++dl)
        a += oc[r * DD + half * 64 + dl] * sw[j * 65 + dl];
      acc[ri] = a;
    }
  }
#pragma unroll
  for (int ri = 0; ri < 8; ++ri) {
    int bp = row0 + 2 * ri + rr;
    mh[(size_t)bp * DD + j] = acc[ri];
  }
}

// ------- Kernel D: score2 (packed f32: two n-columns per accumulator) --------
__global__ __launch_bounds__(256) void k_score2(const float* __restrict__ mh,
                                                const float* __restrict__ shk,
                                                float* __restrict__ sc) {
  int bid = blockIdx.x;
  int swz = (bid & 7) * 128 + (bid >> 3);
  int b = swz >> 4, nt = swz & 15;
  int tid = threadIdx.x; int nl = tid & 31, pg = tid >> 5;
  __shared__ float A[PP * 132];
  for (int idx = tid; idx < PP * DD; idx += 256)
    A[(idx >> 7) * 132 + (idx & 127)] = mh[(size_t)b * PP * DD + idx];
  __syncthreads();

  int na = nt * 64 + nl, nb2 = na + 32;
  int nca = na < NN ? na : NN - 1, ncb = nb2 < NN ? nb2 : NN - 1;
  const float* S = shk + (size_t)b * DD * NN;
  f2 accv[13];
#pragma unroll
  for (int i = 0; i < 13; ++i) accv[i] = splat2(0.f);

  for (int d = 0; d < DD; d += 4) {
    f2 s0, s1, s2, s3;
    s0.x = S[(size_t)(d + 0) * NN + nca]; s0.y = S[(size_t)(d + 0) * NN + ncb];
    s1.x = S[(size_t)(d + 1) * NN + nca]; s1.y = S[(size_t)(d + 1) * NN + ncb];
    s2.x = S[(size_t)(d + 2) * NN + nca]; s2.y = S[(size_t)(d + 2) * NN + ncb];
    s3.x = S[(size_t)(d + 3) * NN + nca]; s3.y = S[(size_t)(d + 3) * NN + ncb];
#pragma unroll
    for (int i = 0; i < 13; ++i) {
      int p = pg + (i << 3);
      if (p < PP) {
        const float4 a4 = *(const float4*)&A[p * 132 + d];
        accv[i] = PKFMA(splat2(a4.x), s0, accv[i]);
        accv[i] = PKFMA(splat2(a4.y), s1, accv[i]);
        accv[i] = PKFMA(splat2(a4.z), s2, accv[i]);
        accv[i] = PKFMA(splat2(a4.w), s3, accv[i]);
      }
    }
  }
#pragma unroll
  for (int i = 0; i < 13; ++i) {
    int p = pg + (i << 3);
    if (p < PP) {
      size_t base = ((size_t)b * PP + p) * NN;
      if (na < NN) sc[base + na] = accv[i].x;
      if (nb2 < NN) sc[base + nb2] = accv[i].y;
    }
  }
}

// ------- Kernel E: tanh clip + edge bias + mask + row softmax (no max pass) ---
__global__ __launch_bounds__(256) void k_finsm(const float* __restrict__ sc,
                                               const float* __restrict__ eb,
                                               const int* __restrict__ cn,
                                               const float* __restrict__ mask,
                                               float* __restrict__ out) {
  int bid = blockIdx.x;
  int bp = (bid & 7) * 800 + (bid >> 3);
  int b = bp / PP;
  int t = threadIdx.x;
  int node = cn[bp];
  const float* scp = sc + (size_t)bp * NN;
  const float* ebp = eb + ((size_t)b * NN + node) * NN;
  const float* mp = mask + (size_t)bp * NN;
  const float inv_sqrtD = 0.08838834764831845f;

  float vals[4];
  float s = 0.f;
#pragma unroll
  for (int i = 0; i < 4; ++i) {
    int n = t + (i << 8);
    if (n < NN) {
      float z = scp[n] * inv_sqrtD;
      float e = EXP2(2.f * LOG2E * z);
      float th10 = 10.f - 20.f * __builtin_amdgcn_rcpf(e + 1.f);
      float lg = th10 + ebp[n] + mp[n];
      float e2 = EXP2(lg * LOG2E);
      vals[i] = e2;
      s += e2;
    } else {
      vals[i] = 0.f;
    }
  }
#pragma unroll
  for (int off = 32; off; off >>= 1) s += __shfl_xor(s, off);
  __shared__ float red[4];
  int w = t >> 6, lane = t & 63;
  if (lane == 0) red[w] = s;
  __syncthreads();
  s = (red[0] + red[1]) + (red[2] + red[3]);
  float inv = 1.f / s;
#pragma unroll
  for (int i = 0; i < 4; ++i) {
    int n = t + (i << 8);
    if (n < NN) out[(size_t)bp * NN + n] = vals[i] * inv;
  }
}

extern "C" void kernel_launch(void* const* d_in, const int* in_sizes, int n_in,
                              void* d_out, int out_size, void* d_ws, size_t ws_size,
                              hipStream_t stream) {
  const float* x    = (const float*)d_in[0];   // encoded_last_node (B,P,D)
  const float* mask = (const float*)d_in[1];   // ninf_mask (B,P,N)
  const float* qf   = (const float*)d_in[2];   // q_first (B,H,P,QD)
  const float* kk   = (const float*)d_in[3];   // k (B,H,NTOT,QD)
  const float* vv   = (const float*)d_in[4];   // v (B,H,NTOT,QD)
  const float* shk  = (const float*)d_in[5];   // single_head_key (B,D,N)
  const float* Wq   = (const float*)d_in[6];   // (128,128)
  const float* MC   = (const float*)d_in[7];   // (128,128)
  const float* eb   = (const float*)d_in[8];   // edge_bias (B,N,N)
  const int*   cn   = (const int*)d_in[9];     // current_node (B,P)

  float* out = (float*)d_out;
  float* ws = (float*)d_ws;
  float* q_ws = ws;                            //   819,200 f
  float* part = ws + 819200;                   // 1,740,800 f (1024*100*17)
  float* mh   = ws + 2560000;                  //   819,200 f
  float* reg  = ws + 3379200;                  // 6,400,000 f shared region:
  unsigned short* m2 = (unsigned short*)reg;   //   mask2 (64*128*1280 ush = 5.24M f)
  float* sc   = reg;                           //   sc overlays m2 (after last m2 read)

  hipLaunchKernelGGL(k_prep, dim3(8592), dim3(256), 0, stream, x, Wq, qf, q_ws, mask, m2);
  hipLaunchKernelGGL(k_mha, dim3(1024), dim3(256), 0, stream, kk, vv, q_ws, m2, part);
  hipLaunchKernelGGL(k_combine, dim3(400), dim3(256), 0, stream, part, MC, mh);
  hipLaunchKernelGGL(k_score2, dim3(1024), dim3(256), 0, stream, mh, shk, sc);
  hipLaunchKernelGGL(k_finsm, dim3(6400), dim3(256), 0, stream, sc, eb, cn, mask, out);
}

// Round 21
// 181.920 us; speedup vs baseline: 1.2247x; 1.0073x over previous
//
#include <hip/hip_runtime.h>
#include <math.h>

#define BB 64
#define PP 100
#define NN 1000
#define DD 128
#define HH 8
#define QDQ 16
#define NTOT 1196
#define QROWS 16
#define LOG2E 1.44269504088896f
#define EXP2(x) __builtin_amdgcn_exp2f(x)

typedef float f2 __attribute__((ext_vector_type(2)));
typedef short s8v __attribute__((ext_vector_type(8)));
typedef float f16v __attribute__((ext_vector_type(16)));

static __device__ __forceinline__ f2 splat2(float v) { f2 r; r.x = v; r.y = v; return r; }
#define PKFMA(a, b, c) __builtin_elementwise_fma((a), (b), (c))

static __device__ __forceinline__ unsigned pkhi(float a, float b) {
  return (__float_as_uint(a) >> 16) | (__float_as_uint(b) & 0xffff0000u);
}
static __device__ __forceinline__ float truncbf(float a) {
  return __uint_as_float(__float_as_uint(a) & 0xffff0000u);
}
#define MFMA32(a, b, c) __builtin_amdgcn_mfma_f32_32x32x16_bf16((a), (b), (c), 0, 0, 0)

// ------- Kernel P: fused {q = q_first + x @ Wq^T} and {mask2 bf16 table} ------
// blocks 0..399: qcalc (16 bp-rows each); blocks 400..8591: mask2 rows (b,q).
__global__ __launch_bounds__(256) void k_prep(const float* __restrict__ x,
                                              const float* __restrict__ Wq,
                                              const float* __restrict__ qf,
                                              float* __restrict__ qout,
                                              const float* __restrict__ mask,
                                              unsigned short* __restrict__ m2) {
  __shared__ float sw[128 * 65];
  __shared__ float xs[QROWS * DD];
  int tid = threadIdx.x;

  if (blockIdx.x < 400) {
    int row0 = blockIdx.x * QROWS;
    for (int i = tid; i < QROWS * DD / 4; i += 256)
      ((float4*)xs)[i] = ((const float4*)(x + (size_t)row0 * DD))[i];

    int j = tid & 127, rr = tid >> 7;
    float acc[8];
#pragma unroll
    for (int i = 0; i < 8; ++i) acc[i] = 0.f;

    for (int half = 0; half < 2; ++half) {
      __syncthreads();
      for (int idx = tid; idx < 128 * 64; idx += 256) {
        int jj = idx >> 6, dl = idx & 63;
        sw[jj * 65 + dl] = Wq[jj * DD + half * 64 + dl];
      }
      __syncthreads();
#pragma unroll
      for (int ri = 0; ri < 8; ++ri) {
        int r = 2 * ri + rr;
        float a = acc[ri];
#pragma unroll 16
        for (int dl = 0; dl < 64; ++dl)
          a += xs[r * DD + half * 64 + dl] * sw[j * 65 + dl];
        acc[ri] = a;
      }
    }
#pragma unroll
    for (int ri = 0; ri < 8; ++ri) {
      int bp = row0 + 2 * ri + rr;
      int b = bp / PP, p = bp % PP;
      int h = j >> 4, qd = j & 15;
      size_t qi = ((size_t)(b * HH + h) * PP + p) * QDQ + qd;
      qout[qi] = acc[ri] + qf[qi];
    }
  } else {
    int t2 = blockIdx.x - 400;
    int b = t2 >> 7, q = t2 & 127;
    unsigned short* dst = m2 + (size_t)(b * 128 + q) * 1280;
    const float* srow = mask + ((size_t)b * PP + (q < PP ? q : PP - 1)) * NN;
    for (int j = tid; j < 1280; j += 256) {
      int h = j >= 640 ? 1 : 0;
      int jj = j - h * 640;
      float val;
      if (q >= PP || jj >= 598) {
        val = -1e4f;
      } else {
        int n = h * 598 + jj;
        val = (n < NN) ? srow[n] * LOG2E - 20.f : -20.f;
      }
      dst[j] = (unsigned short)(__float_as_uint(val) >> 16);
    }
  }
}

// ---------------- Kernel B: MFMA MHA partial (split-bf16, swapped QK^T) -------
// grid = 1024 (XCD-swizzled: 512 bh * 2 halves); block = 256 (4 waves).
// r20-best: truncated-P PV with consistent l = sum(trunc(p)) (2 MFMAs/PV).
__global__ __launch_bounds__(256) void k_mha(const float* __restrict__ kk,
                                             const float* __restrict__ vv,
                                             const float* __restrict__ qws,
                                             const unsigned short* __restrict__ m2,
                                             float* __restrict__ part) {
  int bid = blockIdx.x;
  int swz = (bid & 7) * 128 + (bid >> 3);
  int bh = swz >> 1, half = swz & 1;
  int b = bh >> 3;
  int tid = threadIdx.x;
  int w = tid >> 6, lane = tid & 63;
  int L = lane >> 5, ln = lane & 31;
  bool lo = (L == 0);

  __shared__ __align__(16) char pool[27264];
  char* KspB = pool;                 // [128][80B]: hi 32B | lo 32B | pad 16B
  char* VThB = pool + 10240;         // ushort [16][136] : V^T hi
  char* VTlB = pool + 14592;         // ushort [16][136] : V^T lo
  char* QhB  = pool + 18944;         // ushort [128][16]
  char* QlB  = pool + 23040;

  // ---- stage Q (scaled, split) ----
  {
    const float* qrow = qws + (size_t)bh * (PP * QDQ);
    for (int i = tid; i < 128 * 16; i += 256) {
      int p = i >> 4, qd = i & 15;
      float v = (p < PP) ? qrow[p * QDQ + qd] * (0.25f * LOG2E) : 0.f;
      ((unsigned short*)QhB)[i] = (unsigned short)(__float_as_uint(v) >> 16);
      float rl = v - truncbf(v);
      ((unsigned short*)QlB)[i] = (unsigned short)(__float_as_uint(rl) >> 16);
    }
  }

  const float4* kf4 = (const float4*)kk + (size_t)bh * NTOT * 4;
  const float4* vf4 = (const float4*)vv + (size_t)bh * NTOT * 4;

  f16v Oacc[4];
  float lacc[4];
#pragma unroll
  for (int qt = 0; qt < 4; ++qt) {
    lacc[qt] = 0.f;
#pragma unroll
    for (int r = 0; r < 16; ++r) Oacc[qt][r] = 0.f;
  }
  s8v QhF[4], QlF[4];

  for (int c = 0; c < 5; ++c) {
    __syncthreads();
    // ---- stage 128 keys ----
#pragma unroll
    for (int rep = 0; rep < 2; ++rep) {
      int f = tid + rep * 256;
      int key_l = f >> 2, qd0 = (f & 3) << 2;
      int j = c * 128 + key_l;
      int jc = j < 598 ? j : 597;
      size_t gidx = (size_t)(half * 598 + jc) * 4 + (qd0 >> 2);
      float4 k4 = kf4[gidx];
      unsigned kh01 = pkhi(k4.x, k4.y), kh23 = pkhi(k4.z, k4.w);
      float r0 = k4.x - truncbf(k4.x), r1 = k4.y - truncbf(k4.y);
      float r2 = k4.z - truncbf(k4.z), r3 = k4.w - truncbf(k4.w);
      unsigned kl01 = pkhi(r0, r1), kl23 = pkhi(r2, r3);
      *(uint2*)(KspB + key_l * 80 + qd0 * 2) = make_uint2(kh01, kh23);
      *(uint2*)(KspB + key_l * 80 + 32 + qd0 * 2) = make_uint2(kl01, kl23);
      float4 v4 = vf4[gidx];
      float ve0 = v4.x, ve1 = v4.y, ve2 = v4.z, ve3 = v4.w;
      ((unsigned short*)VThB)[(qd0 + 0) * 136 + key_l] = (unsigned short)(__float_as_uint(ve0) >> 16);
      ((unsigned short*)VThB)[(qd0 + 1) * 136 + key_l] = (unsigned short)(__float_as_uint(ve1) >> 16);
      ((unsigned short*)VThB)[(qd0 + 2) * 136 + key_l] = (unsigned short)(__float_as_uint(ve2) >> 16);
      ((unsigned short*)VThB)[(qd0 + 3) * 136 + key_l] = (unsigned short)(__float_as_uint(ve3) >> 16);
      float w0 = ve0 - truncbf(ve0), w1 = ve1 - truncbf(ve1);
      float w2 = ve2 - truncbf(ve2), w3 = ve3 - truncbf(ve3);
      ((unsigned short*)VTlB)[(qd0 + 0) * 136 + key_l] = (unsigned short)(__float_as_uint(w0) >> 16);
      ((unsigned short*)VTlB)[(qd0 + 1) * 136 + key_l] = (unsigned short)(__float_as_uint(w1) >> 16);
      ((unsigned short*)VTlB)[(qd0 + 2) * 136 + key_l] = (unsigned short)(__float_as_uint(w2) >> 16);
      ((unsigned short*)VTlB)[(qd0 + 3) * 136 + key_l] = (unsigned short)(__float_as_uint(w3) >> 16);
    }
    __syncthreads();
    if (c == 0) {
#pragma unroll
      for (int qt = 0; qt < 4; ++qt) {
        int qr = qt * 32 + ln;
        QhF[qt] = *(const s8v*)(QhB + qr * 32 + L * 16);
        QlF[qt] = *(const s8v*)(QlB + qr * 32 + L * 16);
      }
    }
    // ---- compute this wave's 32-key tile ----
    int ktb = w * 32;
    s8v KhF = *(const s8v*)(KspB + (ktb + ln) * 80 + L * 16);
    s8v KlF = *(const s8v*)(KspB + (ktb + ln) * 80 + 32 + L * 16);
    int vr = ln & 15;
    s8v VhS0 = *(const s8v*)(VThB + vr * 272 + (ktb + L * 8) * 2);
    s8v VhS1 = *(const s8v*)(VThB + vr * 272 + (ktb + 16 + L * 8) * 2);
    s8v VlS0 = *(const s8v*)(VTlB + vr * 272 + (ktb + L * 8) * 2);
    s8v VlS1 = *(const s8v*)(VTlB + vr * 272 + (ktb + 16 + L * 8) * 2);
    size_t mkey = (size_t)half * 640 + c * 128 + ktb + 4 * L;
#pragma unroll
    for (int qt = 0; qt < 4; ++qt) {
      const unsigned short* mrow = m2 + (size_t)(b * 128 + qt * 32 + ln) * 1280 + mkey;
      f16v acc;
#pragma unroll
      for (int g = 0; g < 4; ++g) {
        uint2 md = *(const uint2*)(mrow + g * 8);
        acc[g * 4 + 0] = __uint_as_float(md.x << 16);
        acc[g * 4 + 1] = __uint_as_float(md.x & 0xffff0000u);
        acc[g * 4 + 2] = __uint_as_float(md.y << 16);
        acc[g * 4 + 3] = __uint_as_float(md.y & 0xffff0000u);
      }
      acc = MFMA32(KhF, QhF[qt], acc);
      acc = MFMA32(KhF, QlF[qt], acc);
      acc = MFMA32(KlF, QhF[qt], acc);
      float p[16];
      float ls = 0.f;
#pragma unroll
      for (int r = 0; r < 16; ++r) {
        p[r] = EXP2(acc[r]);
        ls += truncbf(p[r]);               // l consistent with truncated weights
      }
      lacc[qt] += ls;
#pragma unroll
      for (int s = 0; s < 2; ++s) {
        unsigned a0 = pkhi(p[8 * s + 0], p[8 * s + 1]), a1 = pkhi(p[8 * s + 2], p[8 * s + 3]);
        unsigned b0 = pkhi(p[8 * s + 4], p[8 * s + 5]), b1 = pkhi(p[8 * s + 6], p[8 * s + 7]);
        unsigned m0 = lo ? b0 : a0;          // single-shuffle half-exchange
        unsigned m1 = lo ? b1 : a1;
        unsigned s0 = __shfl_xor(m0, 32);
        unsigned s1 = __shfl_xor(m1, 32);
        uint4 phu = make_uint4(lo ? a0 : s0, lo ? a1 : s1, lo ? s0 : b0, lo ? s1 : b1);
        s8v APh = *(s8v*)&phu;
        s8v Vh = s ? VhS1 : VhS0;
        s8v Vl = s ? VlS1 : VlS0;
        Oacc[qt] = MFMA32(APh, Vh, Oacc[qt]);
        Oacc[qt] = MFMA32(APh, Vl, Oacc[qt]);
      }
    }
  }

  // ---- merge 4 waves -> part records [q][17] (unnormalized A + l) ----
  float lf[4];
#pragma unroll
  for (int qt = 0; qt < 4; ++qt) lf[qt] = lacc[qt] + __shfl_xor(lacc[qt], 32);

  __syncthreads();
  float* marea = (float*)pool;                 // [4][100][16]
  float* larea = (float*)(pool + 25600);       // [4][100]
  if (ln < 16) {
#pragma unroll
    for (int qt = 0; qt < 4; ++qt) {
#pragma unroll
      for (int r = 0; r < 16; ++r) {
        int q = qt * 32 + (r & 3) + 8 * (r >> 2) + 4 * L;
        if (q < PP) marea[(w * PP + q) * 16 + ln] = Oacc[qt][r];
      }
    }
  }
  if (lane < 32) {
#pragma unroll
    for (int qt = 0; qt < 4; ++qt) {
      int q = qt * 32 + ln;
      if (q < PP) larea[w * PP + q] = lf[qt];
    }
  }
  __syncthreads();
  for (int idx = tid; idx < PP * 17; idx += 256) {
    int q = idx / 17, e = idx % 17;
    float sv;
    if (e < 16)
      sv = marea[(0 * PP + q) * 16 + e] + marea[(1 * PP + q) * 16 + e]
         + marea[(2 * PP + q) * 16 + e] + marea[(3 * PP + q) * 16 + e];
    else
      sv = larea[0 * PP + q] + larea[1 * PP + q] + larea[2 * PP + q] + larea[3 * PP + q];
    part[((size_t)swz * PP + q) * 17 + e] = sv;
  }
}

// ---------------- Kernel C: merge 2 halves (sum) + mh_combine (LDS GEMM) ------
__global__ __launch_bounds__(256) void k_combine(const float* __restrict__ part,
                                                 const float* __restrict__ MC,
                                                 float* __restrict__ mh) {
  __shared__ float sw[128 * 65];
  __shared__ float oc[QROWS * DD];
  int tid = threadIdx.x;
  int row0 = blockIdx.x * QROWS;

  for (int i = tid; i < QROWS * DD; i += 256) {
    int r = i >> 7, t = i & 127;
    int bp = row0 + r, b = bp / PP, p = bp % PP;
    int qd = t & 15, h = t >> 4;
    int bh = b * HH + h;
    const float* r0 = part + (((size_t)(bh * 2 + 0)) * PP + p) * 17;
    const float* r1 = part + (((size_t)(bh * 2 + 1)) * PP + p) * 17;
    float A = r0[qd] + r1[qd];
    float L = r0[16] + r1[16];
    oc[i] = A / L;
  }

  int j = tid & 127, rr = tid >> 7;
  float acc[8];
#pragma unroll
  for (int i = 0; i < 8; ++i) acc[i] = 0.f;

  for (int half = 0; half < 2; ++half) {
    __syncthreads();
    for (int idx = tid; idx < 128 * 64; idx += 256) {
      int jj = idx >> 6, dl = idx & 63;
      sw[jj * 65 + dl] = MC[jj * DD + half * 64 + dl];
    }
    __syncthreads();
#pragma unroll
    for (int ri = 0; ri < 8; ++ri) {
      int r = 2 * ri + rr;
      float a = acc[ri];
#pragma unroll 16
      for (int dl = 0; dl < 64; ++dl)
        a += oc[r * DD + half * 64 + dl] * sw[j * 65 + dl];
      acc[ri] = a;
    }
  }
#pragma unroll
  for (int ri = 0; ri < 8; ++ri) {
    int bp = row0 + 2 * ri + rr;
    mh[(size_t)bp * DD + j] = acc[ri];
  }
}

// ------- Kernel D: score2 (packed f32: two n-columns per accumulator) --------
__global__ __launch_bounds__(256) void k_score2(const float* __restrict__ mh,
                                                const float* __restrict__ shk,
                                                float* __restrict__ sc) {
  int bid = blockIdx.x;
  int swz = (bid & 7) * 128 + (bid >> 3);
  int b = swz >> 4, nt = swz & 15;
  int tid = threadIdx.x; int nl = tid & 31, pg = tid >> 5;
  __shared__ float A[PP * 132];
  for (int idx = tid; idx < PP * DD; idx += 256)
    A[(idx >> 7) * 132 + (idx & 127)] = mh[(size_t)b * PP * DD + idx];
  __syncthreads();

  int na = nt * 64 + nl, nb2 = na + 32;
  int nca = na < NN ? na : NN - 1, ncb = nb2 < NN ? nb2 : NN - 1;
  const float* S = shk + (size_t)b * DD * NN;
  f2 accv[13];
#pragma unroll
  for (int i = 0; i < 13; ++i) accv[i] = splat2(0.f);

  for (int d = 0; d < DD; d += 4) {
    f2 s0, s1, s2, s3;
    s0.x = S[(size_t)(d + 0) * NN + nca]; s0.y = S[(size_t)(d + 0) * NN + ncb];
    s1.x = S[(size_t)(d + 1) * NN + nca]; s1.y = S[(size_t)(d + 1) * NN + ncb];
    s2.x = S[(size_t)(d + 2) * NN + nca]; s2.y = S[(size_t)(d + 2) * NN + ncb];
    s3.x = S[(size_t)(d + 3) * NN + nca]; s3.y = S[(size_t)(d + 3) * NN + ncb];
#pragma unroll
    for (int i = 0; i < 13; ++i) {
      int p = pg + (i << 3);
      if (p < PP) {
        const float4 a4 = *(const float4*)&A[p * 132 + d];
        accv[i] = PKFMA(splat2(a4.x), s0, accv[i]);
        accv[i] = PKFMA(splat2(a4.y), s1, accv[i]);
        accv[i] = PKFMA(splat2(a4.z), s2, accv[i]);
        accv[i] = PKFMA(splat2(a4.w), s3, accv[i]);
      }
    }
  }
#pragma unroll
  for (int i = 0; i < 13; ++i) {
    int p = pg + (i << 3);
    if (p < PP) {
      size_t base = ((size_t)b * PP + p) * NN;
      if (na < NN) sc[base + na] = accv[i].x;
      if (nb2 < NN) sc[base + nb2] = accv[i].y;
    }
  }
}

// ------- Kernel E: finsm, wave-per-row (no LDS, no barriers, float4) ---------
// grid = 1600 (XCD-swizzled); block = 256 = 4 independent waves, 1 bp row each.
__global__ __launch_bounds__(256) void k_finsm(const float* __restrict__ sc,
                                               const float* __restrict__ eb,
                                               const int* __restrict__ cn,
                                               const float* __restrict__ mask,
                                               float* __restrict__ out) {
  int bid = blockIdx.x;
  int blk = (bid & 7) * 200 + (bid >> 3);      // 0..1599 (1600 % 8 == 0)
  int w = threadIdx.x >> 6, lane = threadIdx.x & 63;
  int bp = blk * 4 + w;                        // 0..6399
  int b = bp / PP;
  int node = cn[bp];
  const float4* scp = (const float4*)(sc + (size_t)bp * NN);
  const float4* ebp = (const float4*)(eb + ((size_t)b * NN + node) * NN);
  const float4* mp  = (const float4*)(mask + (size_t)bp * NN);
  float4* op = (float4*)(out + (size_t)bp * NN);
  const float inv_sqrtD = 0.08838834764831845f;

  float4 v0 = make_float4(0.f, 0.f, 0.f, 0.f), v1 = v0, v2 = v0, v3 = v0;
  float s = 0.f;
#define FEL(vv, comp, s4, e4, m4) { \
    float z = s4.comp * inv_sqrtD; \
    float e = EXP2(2.f * LOG2E * z); \
    float th10 = 10.f - 20.f * __builtin_amdgcn_rcpf(e + 1.f); \
    float lg = th10 + e4.comp + m4.comp; \
    vv.comp = EXP2(lg * LOG2E); }
#define ROW(vv, i) { \
    int idx = lane + ((i) << 6); \
    if (idx < 250) { \
      float4 s4 = scp[idx], e4 = ebp[idx], m4 = mp[idx]; \
      FEL(vv, x, s4, e4, m4) FEL(vv, y, s4, e4, m4) \
      FEL(vv, z, s4, e4, m4) FEL(vv, w, s4, e4, m4) \
      s += (vv.x + vv.y) + (vv.z + vv.w); \
    } }
  ROW(v0, 0) ROW(v1, 1) ROW(v2, 2) ROW(v3, 3)
#undef ROW
#undef FEL
#pragma unroll
  for (int off = 32; off; off >>= 1) s += __shfl_xor(s, off);
  float inv = 1.f / s;
#define WR(vv, i) { \
    int idx = lane + ((i) << 6); \
    if (idx < 250) { \
      float4 o; o.x = vv.x * inv; o.y = vv.y * inv; o.z = vv.z * inv; o.w = vv.w * inv; \
      op[idx] = o; \
    } }
  WR(v0, 0) WR(v1, 1) WR(v2, 2) WR(v3, 3)
#undef WR
}

extern "C" void kernel_launch(void* const* d_in, const int* in_sizes, int n_in,
                              void* d_out, int out_size, void* d_ws, size_t ws_size,
                              hipStream_t stream) {
  const float* x    = (const float*)d_in[0];   // encoded_last_node (B,P,D)
  const float* mask = (const float*)d_in[1];   // ninf_mask (B,P,N)
  const float* qf   = (const float*)d_in[2];   // q_first (B,H,P,QD)
  const float* kk   = (const float*)d_in[3];   // k (B,H,NTOT,QD)
  const float* vv   = (const float*)d_in[4];   // v (B,H,NTOT,QD)
  const float* shk  = (const float*)d_in[5];   // single_head_key (B,D,N)
  const float* Wq   = (const float*)d_in[6];   // (128,128)
  const float* MC   = (const float*)d_in[7];   // (128,128)
  const float* eb   = (const float*)d_in[8];   // edge_bias (B,N,N)
  const int*   cn   = (const int*)d_in[9];     // current_node (B,P)

  float* out = (float*)d_out;
  float* ws = (float*)d_ws;
  float* q_ws = ws;                            //   819,200 f
  float* part = ws + 819200;                   // 1,740,800 f (1024*100*17)
  float* mh   = ws + 2560000;                  //   819,200 f
  float* reg  = ws + 3379200;                  // 6,400,000 f shared region:
  unsigned short* m2 = (unsigned short*)reg;   //   mask2 (64*128*1280 ush = 5.24M f)
  float* sc   = reg;                           //   sc overlays m2 (after last m2 read)

  hipLaunchKernelGGL(k_prep, dim3(8592), dim3(256), 0, stream, x, Wq, qf, q_ws, mask, m2);
  hipLaunchKernelGGL(k_mha, dim3(1024), dim3(256), 0, stream, kk, vv, q_ws, m2, part);
  hipLaunchKernelGGL(k_combine, dim3(400), dim3(256), 0, stream, part, MC, mh);
  hipLaunchKernelGGL(k_score2, dim3(1024), dim3(256), 0, stream, mh, shk, sc);
  hipLaunchKernelGGL(k_finsm, dim3(1600), dim3(256), 0, stream, sc, eb, cn, mask, out);
}